// Round 1
// baseline (1604.525 us; speedup 1.0000x reference)
//
#include <hip/hip_runtime.h>
#include <stdint.h>

#define B_ 8
#define L_ 2048
#define D_ 1024
#define Z_ 128
#define H_ 2048
#define NE_ 16
#define G_ 32
#define MAXPOS_ 2048
#define NMX_ 4224   // D + Z + H + D (u | z | r | hx)
#define NMXP_ 4352  // NMX_ padded to multiple of 256 for 256-tile GEMM
#define EPS_ 1e-5f
#define PC_ 2.0f
#define NTILE_ 16            // L/128 q-tiles
#define NPACK_ 136           // 16*17/2 packed causal tiles
#define TILE_ELEMS_ 16384    // 128*128

typedef short bf16x8 __attribute__((ext_vector_type(8)));
typedef float f32x4 __attribute__((ext_vector_type(4)));

__device__ __forceinline__ float bf2f(uint16_t u) {
  union { uint32_t u; float f; } v; v.u = ((uint32_t)u) << 16; return v.f;
}
__device__ __forceinline__ uint16_t f2bf(float f) {
  union { float f; uint32_t u; } v; v.f = f;
  uint32_t r = (v.u + 0x7FFFu + ((v.u >> 16) & 1u)) >> 16;
  return (uint16_t)r;
}
__device__ __forceinline__ float sigmoidf_(float x) { return 1.f / (1.f + __expf(-x)); }
__device__ __forceinline__ float siluf_(float x) { return x / (1.f + __expf(-x)); }

__device__ __forceinline__ float waveRedSum(float v) {
  #pragma unroll
  for (int m = 32; m; m >>= 1) v += __shfl_xor(v, m, 64);
  return v;
}

// async global->LDS, 16 bytes per lane; lds dst must be waveBase + lane*16
__device__ __forceinline__ void gl2lds(const uint16_t* g, uint16_t* l) {
  __builtin_amdgcn_global_load_lds(
      (const __attribute__((address_space(1))) void*)g,
      (__attribute__((address_space(3))) void*)l, 16, 0, 0);
}

// raw barrier with compiler memory fences on both sides (s_barrier builtin is
// not a compiler memory barrier by itself)
__device__ __forceinline__ void barrier_mem() {
  asm volatile("" ::: "memory");
  __builtin_amdgcn_s_barrier();
  asm volatile("" ::: "memory");
}

// ---------------- fallback when workspace too small ----------------
__global__ __launch_bounds__(256) void k_fallback(float* __restrict__ out, int n, float wsmb) {
  for (int i = blockIdx.x * 256 + threadIdx.x; i < n; i += gridDim.x * 256)
    out[i] = (i == 0) ? wsmb : 0.f;
}

// ---------------- fp32 -> bf16 conversion (weights) ----------------
__global__ __launch_bounds__(256) void k_f2bf(const float* __restrict__ src,
                                              uint16_t* __restrict__ dst, int n) {
  for (int i = blockIdx.x * 256 + threadIdx.x; i < n; i += gridDim.x * 256)
    dst[i] = f2bf(src[i]);
}

// same but zero-fills [n, ntot) (row padding for 256-tile GEMM)
__global__ __launch_bounds__(256) void k_f2bf_pad(const float* __restrict__ src,
                                                  uint16_t* __restrict__ dst, int n, int ntot) {
  for (int i = blockIdx.x * 256 + threadIdx.x; i < ntot; i += gridDim.x * 256)
    dst[i] = (i < n) ? f2bf(src[i]) : (uint16_t)0;
}

// ---------------- TimestepNorm, parallel 3-phase ----------------
__global__ __launch_bounds__(256) void k_tnsum(const float* __restrict__ x,
                                               float* __restrict__ s1g,
                                               float* __restrict__ s2g) {
  const int bg = blockIdx.x;
  const int b = bg / G_, g = bg % G_;
  const int tid = threadIdx.x;
  const int j = tid & 31;
  const int lsub = tid >> 5;
  #pragma unroll
  for (int i = 0; i < 16; ++i) {
    const int l = blockIdx.y * 128 + i * 8 + lsub;
    float v = x[((size_t)(b * L_ + l)) * D_ + g * 32 + j];
    float a = v, sq = v * v;
    #pragma unroll
    for (int m = 1; m <= 16; m <<= 1) { a += __shfl_xor(a, m, 64); sq += __shfl_xor(sq, m, 64); }
    if (j == 0) { s1g[(size_t)bg * L_ + l] = a; s2g[(size_t)bg * L_ + l] = sq; }
  }
}

__global__ __launch_bounds__(64) void k_tnscan(float* __restrict__ s1g,
                                               float* __restrict__ s2g) {
  const int bg = blockIdx.x;
  const int lane = threadIdx.x;
  #pragma unroll
  for (int pass = 0; pass < 2; ++pass) {
    float* gp = (pass ? s2g : s1g) + (size_t)bg * L_;
    float loc[32];
    const int b0 = lane * 32;
    float tot = 0.f;
    #pragma unroll
    for (int t = 0; t < 32; ++t) { loc[t] = gp[b0 + t]; tot += loc[t]; }
    float incl = tot;
    #pragma unroll
    for (int off = 1; off < 64; off <<= 1) {
      float nv = __shfl_up(incl, off, 64);
      if (lane >= off) incl += nv;
    }
    float run = incl - tot;
    #pragma unroll
    for (int t = 0; t < 32; ++t) { run += loc[t]; gp[b0 + t] = run; }
  }
}

__global__ __launch_bounds__(256) void k_tnnorm(const float* __restrict__ x,
                                                const float* __restrict__ s1g,
                                                const float* __restrict__ s2g,
                                                const float* __restrict__ pm,
                                                const float* __restrict__ plv,
                                                const float* __restrict__ w,
                                                const float* __restrict__ bias,
                                                uint16_t* __restrict__ xn) {
  const int bg = blockIdx.x;
  const int b = bg / G_, g = bg % G_;
  const int tid = threadIdx.x;
  const int j = tid & 31;
  const int lsub = tid >> 5;
  const float pmv = pm[g];
  const float pvv = __expf(plv[g]);
  const float wj = w[g * 32 + j];
  const float bj = bias[g * 32 + j];
  const float pterm = PC_ * (pvv + pmv * pmv);
  #pragma unroll
  for (int i = 0; i < 16; ++i) {
    const int l = blockIdx.y * 128 + i * 8 + lsub;
    const size_t idx = ((size_t)(b * L_ + l)) * D_ + g * 32 + j;
    const float v = x[idx];
    const float cnt = PC_ + 32.f * (float)(l + 1);
    const float mean = (PC_ * pmv + s1g[(size_t)bg * L_ + l]) / cnt;
    const float var = (pterm + s2g[(size_t)bg * L_ + l]) / cnt - mean * mean;
    xn[idx] = f2bf((v - mean) * rsqrtf(var + EPS_) * wj + bj);
  }
}

// ---------------- generic 32x32-tiled transpose, batched over z ----------------
template <typename T>
__global__ __launch_bounds__(256) void k_transpose(const T* __restrict__ src,
                                                   T* __restrict__ dst, int R, int C) {
  __shared__ T tile[32][33];
  const size_t batch = (size_t)R * C * blockIdx.z;
  const int c0 = blockIdx.x * 32, r0 = blockIdx.y * 32;
  const int tx = threadIdx.x & 31, ty = threadIdx.x >> 5;
  #pragma unroll
  for (int k = 0; k < 4; ++k) {
    int r = ty + k * 8;
    tile[r][tx] = src[batch + (size_t)(r0 + r) * C + c0 + tx];
  }
  __syncthreads();
  #pragma unroll
  for (int k = 0; k < 4; ++k) {
    int r = ty + k * 8;
    dst[batch + (size_t)(c0 + r) * R + r0 + tx] = tile[tx][r];
  }
}

// ---------------- MultiHeadEMA via chunked linear recurrence ----------------
__global__ __launch_bounds__(64) void k_ema(const uint16_t* __restrict__ xnT,
                                            const float* __restrict__ delta,
                                            const float* __restrict__ alpha,
                                            const float* __restrict__ beta,
                                            const float* __restrict__ gamma,
                                            const float* __restrict__ omega,
                                            float* __restrict__ mxT) {
  __shared__ float hst[64 * NE_];
  const int bd = blockIdx.x;
  const int d = bd & (D_ - 1);
  const int c = threadIdx.x;

  float q[NE_], pb[NE_], gs[NE_];
  #pragma unroll
  for (int n = 0; n < NE_; ++n) {
    float p = sigmoidf_(delta[d * NE_ + n]);
    float a = sigmoidf_(alpha[d * NE_ + n]);
    q[n] = 1.f - p * a;
    pb[n] = p * beta[d * NE_ + n];
    gs[n] = gamma[d * NE_ + n] * 0.25f;
  }

  const uint16_t* xp = xnT + (size_t)bd * L_ + c * 32;
  bf16x8 xin[4];
  #pragma unroll
  for (int s = 0; s < 4; ++s) xin[s] = *(const bf16x8*)(xp + s * 8);

  float h[NE_];
  #pragma unroll
  for (int n = 0; n < NE_; ++n) h[n] = 0.f;

  #pragma unroll
  for (int k = 0; k < 32; ++k) {
    float xv = bf2f((uint16_t)xin[k >> 3][k & 7]);
    #pragma unroll
    for (int n = 0; n < NE_; ++n) h[n] = fmaf(q[n], h[n], pb[n] * xv);
  }
  #pragma unroll
  for (int n = 0; n < NE_; ++n) hst[c * NE_ + n] = h[n];
  __syncthreads();

  if (c < NE_) {
    float qq = q[c];
    float q32 = qq * qq; q32 *= q32; q32 *= q32; q32 *= q32; q32 *= q32;  // q^32
    float hi = 0.f;
    for (int cc = 0; cc < 64; ++cc) {
      float cur = hst[cc * NE_ + c];
      hst[cc * NE_ + c] = hi;
      hi = fmaf(q32, hi, cur);
    }
  }
  __syncthreads();

  #pragma unroll
  for (int n = 0; n < NE_; ++n) h[n] = hst[c * NE_ + n];
  const float om = omega[d];
  float* op = mxT + (size_t)bd * L_ + c * 32;
  f32x4 ov;
  #pragma unroll
  for (int k = 0; k < 32; ++k) {
    float xv = bf2f((uint16_t)xin[k >> 3][k & 7]);
    float accv = 0.f;
    #pragma unroll
    for (int n = 0; n < NE_; ++n) {
      h[n] = fmaf(q[n], h[n], pb[n] * xv);
      accv = fmaf(gs[n], h[n], accv);
    }
    ov[k & 3] = accv + om * xv;
    if ((k & 3) == 3) *(f32x4*)(op + (k & ~3)) = ov;
  }
}

// ---------------- RMS norm over D ----------------
__global__ __launch_bounds__(256) void k_rms(const float* __restrict__ mx,
                                             const float* __restrict__ w,
                                             uint16_t* __restrict__ mxn) {
  __shared__ float red[4];
  const size_t row = blockIdx.x;
  const int tid = threadIdx.x;
  float ss = 0.f;
  #pragma unroll
  for (int i = 0; i < 4; ++i) {
    float v = mx[row * D_ + tid + i * 256];
    ss += v * v;
  }
  ss = waveRedSum(ss);
  if ((tid & 63) == 0) red[tid >> 6] = ss;
  __syncthreads();
  ss = red[0] + red[1] + red[2] + red[3];
  const float scale = rsqrtf(ss * (1.f / D_) + EPS_);
  #pragma unroll
  for (int i = 0; i < 4; ++i) {
    int dcol = tid + i * 256;
    mxn[row * D_ + dcol] = f2bf(mx[row * D_ + dcol] * scale * w[dcol]);
  }
}

// ---------------- q/k prep from z ----------------
__global__ __launch_bounds__(256) void k_qkprep(const float* __restrict__ z,
                                                const float* __restrict__ qg,
                                                const float* __restrict__ qb,
                                                uint16_t* __restrict__ q,
                                                uint16_t* __restrict__ k, int n) {
  for (int i = blockIdx.x * 256 + threadIdx.x; i < n; i += gridDim.x * 256) {
    int zc = i & (Z_ - 1);
    float v = z[i];
    q[i] = f2bf((v * qg[zc] + qb[zc]) * 0.08838834764831845f);
    k[i] = f2bf(v * qg[Z_ + zc] + qb[Z_ + zc]);
  }
}

// ==================================================================
// 256x256-tile, BK=64, 8-wave, phase-interleaved counted-vmcnt GEMM
// C = A(MxK) @ B(NxK)^T, fused epilogues:
//  MODE 0: V     out = silu(acc + bv[col])               -> bf16 v
//  MODE 1: BASE  acc + bmx[col], split u/z/r/hx (col-guarded at NMX_)
//  MODE 4: WH    g=silu(acc+hx); out = x + u*(g-x)        -> f32 d_out
//
// LDS layout (uint16 offsets): buf c in [c*32768, +32768):
//   A at +0, B at +16384; within each: K-half kh at kh*8192,
//   row-major [256 rows][32 cols], 16B granule XOR-swizzled by (row>>2)&3.
// Staging: global_load_lds with pre-swizzled SOURCE (linear LDS dest),
// 2 loads per thread per (matrix, K-half).  vmcnt(4) twice per K-tile,
// never 0 in the main loop (4 loads always in flight).
// ==================================================================

#define STG(c, kh, kb, MAT) do {                                              \
    const uint16_t* _g = ((MAT) ? gB : gA) + (kb) + (kh) * 32;                \
    uint16_t* _l = sm + (c) * 32768 + (MAT) * 16384 + (kh) * 8192 + t * 8;    \
    gl2lds(_g, _l); gl2lds(_g + rsk, _l + 4096);                              \
  } while (0)

#define LDA4(c, kh, ih) do {                                                  \
    _Pragma("unroll")                                                         \
    for (int _i = 0; _i < 4; ++_i)                                            \
      af[_i] = *(const bf16x8*)&sm[(c) * 32768 + (kh) * 8192 + aOff +         \
                                   ((ih) * 4 + _i) * 512];                    \
  } while (0)

#define LDB4(c, kh) do {                                                      \
    _Pragma("unroll")                                                         \
    for (int _j = 0; _j < 4; ++_j)                                            \
      bfr[_j] = *(const bf16x8*)&sm[(c) * 32768 + (kh) * 8192 + bOff +        \
                                    _j * 512];                                \
  } while (0)

#define MM16(ih) do {                                                         \
    __builtin_amdgcn_s_setprio(1);                                            \
    _Pragma("unroll")                                                         \
    for (int _i = 0; _i < 4; ++_i) {                                          \
      _Pragma("unroll")                                                       \
      for (int _j = 0; _j < 4; ++_j)                                          \
        acc[(ih) * 4 + _i][_j] = __builtin_amdgcn_mfma_f32_16x16x32_bf16(     \
            af[_i], bfr[_j], acc[(ih) * 4 + _i][_j], 0, 0, 0);                \
    }                                                                         \
    __builtin_amdgcn_s_setprio(0);                                            \
  } while (0)

template <int MODE>
__global__ __launch_bounds__(512, 2) void k_gemm256(
    const uint16_t* __restrict__ A, const uint16_t* __restrict__ Bm,
    int N, int K,
    const float* __restrict__ bias,
    float* __restrict__ outf, uint16_t* __restrict__ outb,
    uint16_t* __restrict__ ubuf, float* __restrict__ zbuf,
    uint16_t* __restrict__ rbuf, float* __restrict__ hxbuf,
    const float* __restrict__ x0) {
  __shared__ uint16_t sm[65536];  // 128 KiB
  const int t = threadIdx.x;
  const int lane = t & 63, wave = t >> 6;
  const int quad = lane >> 4, r16 = lane & 15;
  const int wm = wave >> 2, wn = wave & 3;

  // bijective XCD swizzle (all grids are multiples of 8 blocks)
  const int nbx = gridDim.x;
  const int nwg = nbx * gridDim.y;
  int lid = blockIdx.y * nbx + blockIdx.x;
  const int cpx = nwg >> 3;
  lid = (lid & 7) * cpx + (lid >> 3);
  const int bm = (lid % nbx) * 256;
  const int bn = (lid / nbx) * 256;

  f32x4 acc[8][4];
  const f32x4 zf = {0.f, 0.f, 0.f, 0.f};
  #pragma unroll
  for (int i = 0; i < 8; ++i)
    #pragma unroll
    for (int j = 0; j < 4; ++j) acc[i][j] = zf;

  // staging addresses: thread t, load q in {0,1}:
  //   lds row = q*128 + (t>>2), physical granule G = t&3
  //   logical granule g = G ^ ((row>>2)&3) = (t&3) ^ ((t>>4)&3)
  const int srow = t >> 2;
  const int sg = (((t & 3) ^ ((t >> 4) & 3)) << 3);
  const uint16_t* gA = A + (size_t)(bm + srow) * K + sg;
  const uint16_t* gB = Bm + (size_t)(bn + srow) * K + sg;
  const size_t rsk = (size_t)128 * K;

  // fragment read offsets: logical granule = quad, physical = quad ^ ((row>>2)&3)
  const int G8 = (quad ^ ((r16 >> 2) & 3)) << 3;
  const int aOff = (wm * 128 + r16) * 32 + G8;
  const int bOff = 16384 + (wn * 64 + r16) * 32 + G8;

  const int NT = K >> 6;

  // prologue: stage tile 0, order [Ak0 Ak0 Bk0 Bk0 Ak1 Ak1 Bk1 Bk1]
  STG(0, 0, 0, 0); STG(0, 0, 0, 1); STG(0, 1, 0, 0); STG(0, 1, 0, 1);
  asm volatile("s_waitcnt vmcnt(4)" ::: "memory");  // Ak0,Bk0 landed
  barrier_mem();

  bf16x8 af[4], bfr[4];
  for (int tt = 0; tt < NT; ++tt) {
    const int c = tt & 1, cn = c ^ 1;
    const int kbn = (tt + 1) << 6;
    const bool pf = (tt + 1 < NT);
    // ---- phase 0: kh0, row-half 0 ----
    LDA4(c, 0, 0); LDB4(c, 0);
    if (pf) STG(cn, 0, kbn, 0);
    MM16(0);
    barrier_mem();
    // ---- phase 1: kh0, row-half 1 (B frags held) ----
    LDA4(c, 0, 1);
    if (pf) STG(cn, 0, kbn, 1);
    MM16(1);
    // mid: need this tile's Ak1,Bk1; queue = [Ak1 Ak1 Bk1 Bk1 (+4 next-tile)]
    if (pf) asm volatile("s_waitcnt vmcnt(4)" ::: "memory");
    else    asm volatile("s_waitcnt vmcnt(0)" ::: "memory");
    barrier_mem();
    // ---- phase 2: kh1, row-half 0 ----
    LDA4(c, 1, 0); LDB4(c, 1);
    if (pf) STG(cn, 1, kbn, 0);
    MM16(0);
    barrier_mem();
    // ---- phase 3: kh1, row-half 1 ----
    LDA4(c, 1, 1);
    if (pf) STG(cn, 1, kbn, 1);
    MM16(1);
    // end: need next tile's Ak0,Bk0; queue = next tile's 8 loads
    if (pf) asm volatile("s_waitcnt vmcnt(4)" ::: "memory");
    barrier_mem();
  }

  // ---- epilogue ----
  #pragma unroll
  for (int gi = 0; gi < 8; ++gi) {
    #pragma unroll
    for (int j = 0; j < 4; ++j) {
      #pragma unroll
      for (int r = 0; r < 4; ++r) {
        const int row = bm + wm * 128 + gi * 16 + quad * 4 + r;
        const int col = bn + wn * 64 + j * 16 + r16;
        float val = acc[gi][j][r];
        if (MODE == 0) {
          outb[(size_t)row * N + col] = f2bf(siluf_(val + bias[col]));
        } else if (MODE == 1) {
          if (col < NMX_) {
            val += bias[col];
            if (col < D_)                 ubuf[(size_t)row * D_ + col] = f2bf(sigmoidf_(val));
            else if (col < D_ + Z_)       zbuf[(size_t)row * Z_ + (col - D_)] = siluf_(val);
            else if (col < D_ + Z_ + H_)  rbuf[(size_t)row * H_ + (col - D_ - Z_)] = f2bf(siluf_(val));
            else                          hxbuf[(size_t)row * D_ + (col - D_ - Z_ - H_)] = val;
          }
        } else {
          const size_t idx = (size_t)row * N + col;
          float g = siluf_(val + hxbuf[idx]);   // read hx (d_out) ...
          float xv = x0[idx];
          outf[idx] = xv + bf2f(ubuf[idx]) * (g - xv);  // ... then write same addr
        }
      }
    }
  }
}

#undef STG
#undef LDA4
#undef LDB4
#undef MM16

// ---- fused QK^T + rel_bias + causal softmax -> packed-triangular P (bf16) ----
__global__ __launch_bounds__(256) void k_qksm(
    const uint16_t* __restrict__ qg, const uint16_t* __restrict__ kg,
    const float* __restrict__ relb, uint16_t* __restrict__ Pp) {
  __shared__ uint16_t Ks[128 * 128];
  __shared__ float relwin[256];
  const int qt = blockIdx.x;
  const int bl = blockIdx.y;
  const int tid = threadIdx.x;
  const int w = tid >> 6, lane = tid & 63;
  const int quad = lane >> 4, r16 = lane & 15;
  const uint16_t* qb_b = qg + (size_t)bl * L_ * Z_;
  const uint16_t* kb_b = kg + (size_t)bl * L_ * Z_;
  uint16_t* P_b = Pp + (size_t)bl * NPACK_ * TILE_ELEMS_;

  bf16x8 aq[2][4];
  #pragma unroll
  for (int i = 0; i < 2; ++i)
    #pragma unroll
    for (int s = 0; s < 4; ++s)
      aq[i][s] = *(const bf16x8*)&qb_b[(size_t)(qt * 128 + w * 32 + i * 16 + r16) * Z_ +
                                       s * 32 + quad * 8];

  float m8[8], l8[8];
  #pragma unroll
  for (int t = 0; t < 8; ++t) { m8[t] = -3.4e38f; l8[t] = 0.f; }

  const f32x4 zf = {0.f, 0.f, 0.f, 0.f};

  // ---- phase 1: stats ----
  for (int kt = 0; kt <= qt; ++kt) {
    __syncthreads();
    const uint16_t* src = kb_b + (size_t)kt * 128 * Z_;
    #pragma unroll
    for (int s2 = 0; s2 < 8; ++s2)
      gl2lds(src + s2 * 2048 + tid * 8, Ks + s2 * 2048 + tid * 8);
    if (tid < 255) relwin[tid] = relb[2047 + (kt - qt) * 128 - 127 + tid];
    __syncthreads();
    #pragma unroll
    for (int j = 0; j < 8; ++j) {
      f32x4 a0 = zf, a1 = zf;
      #pragma unroll
      for (int s = 0; s < 4; ++s) {
        bf16x8 bk = *(const bf16x8*)&Ks[(j * 16 + r16) * 128 + s * 32 + quad * 8];
        a0 = __builtin_amdgcn_mfma_f32_16x16x32_bf16(aq[0][s], bk, a0, 0, 0, 0);
        a1 = __builtin_amdgcn_mfma_f32_16x16x32_bf16(aq[1][s], bk, a1, 0, 0, 0);
      }
      #pragma unroll
      for (int i = 0; i < 2; ++i) {
        const f32x4 av = i ? a1 : a0;
        #pragma unroll
        for (int r = 0; r < 4; ++r) {
          const int rloc = w * 32 + i * 16 + quad * 4 + r;
          const int cloc = j * 16 + r16;
          if (kt < qt || cloc <= rloc) {
            const float v = av[r] + relwin[cloc - rloc + 127];
            const int t = i * 4 + r;
            const float mn = fmaxf(m8[t], v);
            l8[t] = l8[t] * __expf(m8[t] - mn) + __expf(v - mn);
            m8[t] = mn;
          }
        }
      }
    }
  }

  #pragma unroll
  for (int t = 0; t < 8; ++t) {
    #pragma unroll
    for (int msk = 1; msk <= 8; msk <<= 1) {
      const float mo = __shfl_xor(m8[t], msk, 64);
      const float lo = __shfl_xor(l8[t], msk, 64);
      const float mn = fmaxf(m8[t], mo);
      l8[t] = l8[t] * __expf(m8[t] - mn) + lo * __expf(mo - mn);
      m8[t] = mn;
    }
    l8[t] = 1.f / l8[t];
  }

  // ---- phase 2: recompute, normalize, write packed P ----
  for (int kt = 0; kt <= qt; ++kt) {
    __syncthreads();
    const uint16_t* src = kb_b + (size_t)kt * 128 * Z_;
    #pragma unroll
    for (int s2 = 0; s2 < 8; ++s2)
      gl2lds(src + s2 * 2048 + tid * 8, Ks + s2 * 2048 + tid * 8);
    if (tid < 255) relwin[tid] = relb[2047 + (kt - qt) * 128 - 127 + tid];
    __syncthreads();
    uint16_t* Pt = P_b + (size_t)(qt * (qt + 1) / 2 + kt) * TILE_ELEMS_;
    #pragma unroll
    for (int j = 0; j < 8; ++j) {
      f32x4 a0 = zf, a1 = zf;
      #pragma unroll
      for (int s = 0; s < 4; ++s) {
        bf16x8 bk = *(const bf16x8*)&Ks[(j * 16 + r16) * 128 + s * 32 + quad * 8];
        a0 = __builtin_amdgcn_mfma_f32_16x16x32_bf16(aq[0][s], bk, a0, 0, 0, 0);
        a1 = __builtin_amdgcn_mfma_f32_16x16x32_bf16(aq[1][s], bk, a1, 0, 0, 0);
      }
      #pragma unroll
      for (int i = 0; i < 2; ++i) {
        const f32x4 av = i ? a1 : a0;
        #pragma unroll
        for (int r = 0; r < 4; ++r) {
          const int rloc = w * 32 + i * 16 + quad * 4 + r;
          const int cloc = j * 16 + r16;
          const int t = i * 4 + r;
          float p = 0.f;
          if (kt < qt || cloc <= rloc) {
            const float v = av[r] + relwin[cloc - rloc + 127];
            p = __expf(v - m8[t]) * l8[t];
          }
          Pt[rloc * 128 + cloc] = f2bf(p);
        }
      }
    }
  }
}

// ---- PV GEMM: hr = (P @ V) * r, packed-triangular P, in-place over r ----
__global__ __launch_bounds__(256) void k_pv(
    const uint16_t* __restrict__ Pp, const uint16_t* __restrict__ vT,
    uint16_t* __restrict__ rh) {
  __shared__ uint16_t As[128 * 32];
  __shared__ uint16_t Bs[128 * 32];
  const int qt = blockIdx.x;
  const int bn = blockIdx.y * 128;
  const int bl = blockIdx.z;
  const uint16_t* P_b = Pp + (size_t)bl * NPACK_ * TILE_ELEMS_;
  const uint16_t* v_b = vT + (size_t)bl * H_ * L_;
  uint16_t* rh_b = rh + (size_t)bl * L_ * H_;

  const int tid = threadIdx.x;
  const int wave = tid >> 6, lane = tid & 63;
  const int quad = lane >> 4, r16 = lane & 15;
  const int wm = wave >> 1, wn = wave & 1;
  const int rowW = wm * 64, colW = wn * 64;

  f32x4 acc[4][4];
  const f32x4 zf = {0.f, 0.f, 0.f, 0.f};
  #pragma unroll
  for (int i = 0; i < 4; ++i)
    #pragma unroll
    for (int j = 0; j < 4; ++j) acc[i][j] = zf;

  const int rA = tid >> 2;
  const int sg = (tid & 3) * 8;
  uint16_t* lA0 = As + tid * 8;
  uint16_t* lA1 = As + 2048 + tid * 8;
  uint16_t* lB0 = Bs + tid * 8;
  uint16_t* lB1 = Bs + 2048 + tid * 8;

  for (int kt = 0; kt <= qt; ++kt) {
    const uint16_t* At = P_b + (size_t)(qt * (qt + 1) / 2 + kt) * TILE_ELEMS_;
    #pragma unroll
    for (int ks = 0; ks < 4; ++ks) {
      const int kb = kt * 128 + ks * 32;
      __syncthreads();
      gl2lds(At + rA * 128 + ks * 32 + sg, lA0);
      gl2lds(At + (rA + 64) * 128 + ks * 32 + sg, lA1);
      gl2lds(v_b + (size_t)(bn + rA) * L_ + kb + sg, lB0);
      gl2lds(v_b + (size_t)(bn + 64 + rA) * L_ + kb + sg, lB1);
      __syncthreads();
      bf16x8 af[4], bfr[4];
      #pragma unroll
      for (int i = 0; i < 4; ++i)
        af[i] = *(const bf16x8*)&As[(rowW + i * 16 + r16) * 32 + quad * 8];
      #pragma unroll
      for (int j = 0; j < 4; ++j)
        bfr[j] = *(const bf16x8*)&Bs[(colW + j * 16 + r16) * 32 + quad * 8];
      #pragma unroll
      for (int i = 0; i < 4; ++i)
        #pragma unroll
        for (int j = 0; j < 4; ++j)
          acc[i][j] = __builtin_amdgcn_mfma_f32_16x16x32_bf16(af[i], bfr[j], acc[i][j], 0, 0, 0);
    }
  }

  #pragma unroll
  for (int i = 0; i < 4; ++i) {
    #pragma unroll
    for (int j = 0; j < 4; ++j) {
      #pragma unroll
      for (int r = 0; r < 4; ++r) {
        const int row = qt * 128 + rowW + i * 16 + quad * 4 + r;
        const int col = bn + colW + j * 16 + r16;
        const size_t idx = (size_t)row * H_ + col;
        const float rv = bf2f(rh_b[idx]);
        rh_b[idx] = f2bf(acc[i][j][r] * rv);
      }
    }
  }
}

extern "C" void kernel_launch(void* const* d_in, const int* in_sizes, int n_in,
                              void* d_out, int out_size, void* d_ws, size_t ws_size,
                              hipStream_t stream) {
  (void)in_sizes; (void)n_in;
  const float* x         = (const float*)d_in[0];
  const float* prior_mean= (const float*)d_in[1];
  const float* prior_logv= (const float*)d_in[2];
  const float* tn_w      = (const float*)d_in[3];
  const float* tn_b      = (const float*)d_in[4];
  const float* delta     = (const float*)d_in[5];
  const float* alpha     = (const float*)d_in[6];
  const float* ema_beta  = (const float*)d_in[7];
  const float* ema_gamma = (const float*)d_in[8];
  const float* omega     = (const float*)d_in[9];
  const float* rms_w     = (const float*)d_in[10];
  const float* Wv        = (const float*)d_in[11];
  const float* bv        = (const float*)d_in[12];
  const float* Wmx       = (const float*)d_in[13];
  const float* bmx       = (const float*)d_in[14];
  const float* Wh        = (const float*)d_in[15];
  const float* qk_gamma  = (const float*)d_in[16];
  const float* qk_beta   = (const float*)d_in[17];
  const float* rel_bias  = (const float*)d_in[18];
  float* out = (float*)d_out;

  const int BL = B_ * L_;
  const size_t MB = 1024 * 1024;
  const size_t REQUIRED = 256 * MB;

  if (ws_size < REQUIRED) {
    k_fallback<<<dim3(4096), dim3(256), 0, stream>>>(out, out_size, (float)(ws_size / MB));
    return;
  }

  char* p = (char*)d_ws;
  // A [0,32): xn (bf16) -> ubuf (bf16)
  uint16_t* xn   = (uint16_t*)(p);
  uint16_t* ubuf = (uint16_t*)(p);
  // B [32,64): s1s2 (4MB, tnorm only) -> xnT -> mxn
  float*    s1g  = (float*)   (p + 32 * MB);
  float*    s2g  = (float*)   (p + 34 * MB);
  uint16_t* xnT  = (uint16_t*)(p + 32 * MB);
  uint16_t* mxn  = (uint16_t*)(p + 32 * MB);
  // C [64,128): vbuf -> mx (f32) -> rbuf/hr (in-place PV)
  uint16_t* vbuf = (uint16_t*)(p + 64 * MB);
  float*    mx   = (float*)   (p + 64 * MB);
  uint16_t* rbuf = (uint16_t*)(p + 64 * MB);
  // D [128,192): wv_b -> vT
  uint16_t* wv_b = (uint16_t*)(p + 128 * MB);
  uint16_t* vT   = (uint16_t*)(p + 128 * MB);
  // E [192,256): wmx_b(8.91, padded) | z(8) | qb(4) | kb(4) | Ppack(35.65)
  uint16_t* wmx_b = (uint16_t*)(p + 192 * MB);
  uint16_t* wh_b  = (uint16_t*)(p + 192 * MB);
  float*    zb    = (float*)   (p + 201 * MB);
  uint16_t* qb    = (uint16_t*)(p + 209 * MB);
  uint16_t* kb2   = (uint16_t*)(p + 213 * MB);
  uint16_t* Ppack = (uint16_t*)(p + 217 * MB);
  // d_out doubles as: mxT f32 (EMA out) -> hx f32 (BASE out) -> out
  float* mxT = out;
  float* hx  = out;

  // 1. weights -> bf16 (Wmx padded to NMXP_ rows, zero-filled)
  k_f2bf<<<dim3(1024), dim3(256), 0, stream>>>(Wv, wv_b, H_ * D_);
  k_f2bf_pad<<<dim3(2048), dim3(256), 0, stream>>>(Wmx, wmx_b, NMX_ * D_, NMXP_ * D_);
  // 2. timestep norm (3-phase parallel) -> xn
  k_tnsum<<<dim3(B_ * G_, 16), dim3(256), 0, stream>>>(x, s1g, s2g);
  k_tnscan<<<dim3(B_ * G_), dim3(64), 0, stream>>>(s1g, s2g);
  k_tnnorm<<<dim3(B_ * G_, 16), dim3(256), 0, stream>>>(
      x, s1g, s2g, prior_mean, prior_logv, tn_w, tn_b, xn);
  // 3. xn -> xnT (overwrites dead s1s2)
  k_transpose<uint16_t><<<dim3(D_ / 32, L_ / 32, B_), dim3(256), 0, stream>>>(xn, xnT, L_, D_);
  // 4. v = silu(xn @ Wv^T + bv) -> vbuf
  k_gemm256<0><<<dim3(BL / 256, H_ / 256), dim3(512), 0, stream>>>(
      xn, wv_b, H_, D_, bv, nullptr, vbuf,
      nullptr, nullptr, nullptr, nullptr, nullptr);
  // 5. v -> vT (overwrites dead wv_b)
  k_transpose<uint16_t><<<dim3(H_ / 32, L_ / 32, B_), dim3(256), 0, stream>>>(vbuf, vT, L_, H_);
  // 6. EMA: xnT -> mxT (d_out)
  k_ema<<<dim3(B_ * D_), dim3(64), 0, stream>>>(xnT, delta, alpha, ema_beta, ema_gamma, omega, mxT);
  // 7. mxT -> mx (overwrites dead vbuf)
  k_transpose<float><<<dim3(L_ / 32, D_ / 32, B_), dim3(256), 0, stream>>>(mxT, mx, D_, L_);
  // 8. RMS norm -> mxn (overwrites dead xnT)
  k_rms<<<dim3(BL), dim3(256), 0, stream>>>(mx, rms_w, mxn);
  // 9. BASE GEMM -> u(A), z(E), r(C), hx(d_out)
  k_gemm256<1><<<dim3(BL / 256, NMXP_ / 256), dim3(512), 0, stream>>>(
      mxn, wmx_b, NMXP_, D_, bmx, nullptr, nullptr,
      ubuf, zb, rbuf, hx, nullptr);
  // 10. q,k from z
  k_qkprep<<<dim3(1024), dim3(256), 0, stream>>>(zb, qk_gamma, qk_beta, qb, kb2, BL * Z_);
  // 11. fused QK+softmax -> packed P (all 8 batches, one dispatch)
  k_qksm<<<dim3(NTILE_, B_), dim3(256), 0, stream>>>(qb, kb2, rel_bias, Ppack);
  // 12. PV GEMM, hr = (P@V)*r in-place over rbuf (one dispatch)
  k_pv<<<dim3(NTILE_, H_ / 128, B_), dim3(256), 0, stream>>>(Ppack, vT, rbuf);
  // 13. Wh -> bf16 (over dead wmx_b)
  k_f2bf<<<dim3(1024), dim3(256), 0, stream>>>(Wh, wh_b, D_ * H_);
  // 14. final: g = silu(hx + hr@Wh^T); out = x + u*(g-x)
  k_gemm256<4><<<dim3(BL / 256, D_ / 256), dim3(512), 0, stream>>>(
      rbuf, wh_b, D_, H_, nullptr, out, nullptr,
      ubuf, nullptr, nullptr, hx, x);
}

// Round 2
// 1273.344 us; speedup vs baseline: 1.2601x; 1.2601x over previous
//
#include <hip/hip_runtime.h>
#include <stdint.h>

#define B_ 8
#define L_ 2048
#define D_ 1024
#define Z_ 128
#define H_ 2048
#define NE_ 16
#define G_ 32
#define MAXPOS_ 2048
#define NMX_ 4224   // D + Z + H + D (u | z | r | hx)
#define NMXP_ 4352  // NMX_ padded to multiple of 256 for 256-tile GEMM
#define EPS_ 1e-5f
#define PC_ 2.0f
#define NTILE_ 16            // L/128 q-tiles
#define NPACK_ 136           // 16*17/2 packed causal tiles
#define TILE_ELEMS_ 16384    // 128*128

typedef short bf16x8 __attribute__((ext_vector_type(8)));
typedef float f32x4 __attribute__((ext_vector_type(4)));

__device__ __forceinline__ float bf2f(uint16_t u) {
  union { uint32_t u; float f; } v; v.u = ((uint32_t)u) << 16; return v.f;
}
__device__ __forceinline__ uint16_t f2bf(float f) {
  union { float f; uint32_t u; } v; v.f = f;
  uint32_t r = (v.u + 0x7FFFu + ((v.u >> 16) & 1u)) >> 16;
  return (uint16_t)r;
}
__device__ __forceinline__ float sigmoidf_(float x) { return 1.f / (1.f + __expf(-x)); }
__device__ __forceinline__ float siluf_(float x) { return x / (1.f + __expf(-x)); }

__device__ __forceinline__ float waveRedSum(float v) {
  #pragma unroll
  for (int m = 32; m; m >>= 1) v += __shfl_xor(v, m, 64);
  return v;
}

// async global->LDS, 16 bytes per lane; lds dst must be waveBase + lane*16
__device__ __forceinline__ void gl2lds(const uint16_t* g, uint16_t* l) {
  __builtin_amdgcn_global_load_lds(
      (const __attribute__((address_space(1))) void*)g,
      (__attribute__((address_space(3))) void*)l, 16, 0, 0);
}

// ---------------- fallback when workspace too small ----------------
__global__ __launch_bounds__(256) void k_fallback(float* __restrict__ out, int n, float wsmb) {
  for (int i = blockIdx.x * 256 + threadIdx.x; i < n; i += gridDim.x * 256)
    out[i] = (i == 0) ? wsmb : 0.f;
}

// ---------------- fp32 -> bf16 conversion (weights) ----------------
__global__ __launch_bounds__(256) void k_f2bf(const float* __restrict__ src,
                                              uint16_t* __restrict__ dst, int n) {
  for (int i = blockIdx.x * 256 + threadIdx.x; i < n; i += gridDim.x * 256)
    dst[i] = f2bf(src[i]);
}

// same but zero-fills [n, ntot) (row padding for 256-tile GEMM)
__global__ __launch_bounds__(256) void k_f2bf_pad(const float* __restrict__ src,
                                                  uint16_t* __restrict__ dst, int n, int ntot) {
  for (int i = blockIdx.x * 256 + threadIdx.x; i < ntot; i += gridDim.x * 256)
    dst[i] = (i < n) ? f2bf(src[i]) : (uint16_t)0;
}

// ---------------- TimestepNorm, parallel 3-phase ----------------
__global__ __launch_bounds__(256) void k_tnsum(const float* __restrict__ x,
                                               float* __restrict__ s1g,
                                               float* __restrict__ s2g) {
  const int bg = blockIdx.x;
  const int b = bg / G_, g = bg % G_;
  const int tid = threadIdx.x;
  const int j = tid & 31;
  const int lsub = tid >> 5;
  #pragma unroll
  for (int i = 0; i < 16; ++i) {
    const int l = blockIdx.y * 128 + i * 8 + lsub;
    float v = x[((size_t)(b * L_ + l)) * D_ + g * 32 + j];
    float a = v, sq = v * v;
    #pragma unroll
    for (int m = 1; m <= 16; m <<= 1) { a += __shfl_xor(a, m, 64); sq += __shfl_xor(sq, m, 64); }
    if (j == 0) { s1g[(size_t)bg * L_ + l] = a; s2g[(size_t)bg * L_ + l] = sq; }
  }
}

__global__ __launch_bounds__(64) void k_tnscan(float* __restrict__ s1g,
                                               float* __restrict__ s2g) {
  const int bg = blockIdx.x;
  const int lane = threadIdx.x;
  #pragma unroll
  for (int pass = 0; pass < 2; ++pass) {
    float* gp = (pass ? s2g : s1g) + (size_t)bg * L_;
    float loc[32];
    const int b0 = lane * 32;
    float tot = 0.f;
    #pragma unroll
    for (int t = 0; t < 32; ++t) { loc[t] = gp[b0 + t]; tot += loc[t]; }
    float incl = tot;
    #pragma unroll
    for (int off = 1; off < 64; off <<= 1) {
      float nv = __shfl_up(incl, off, 64);
      if (lane >= off) incl += nv;
    }
    float run = incl - tot;
    #pragma unroll
    for (int t = 0; t < 32; ++t) { run += loc[t]; gp[b0 + t] = run; }
  }
}

__global__ __launch_bounds__(256) void k_tnnorm(const float* __restrict__ x,
                                                const float* __restrict__ s1g,
                                                const float* __restrict__ s2g,
                                                const float* __restrict__ pm,
                                                const float* __restrict__ plv,
                                                const float* __restrict__ w,
                                                const float* __restrict__ bias,
                                                uint16_t* __restrict__ xn) {
  const int bg = blockIdx.x;
  const int b = bg / G_, g = bg % G_;
  const int tid = threadIdx.x;
  const int j = tid & 31;
  const int lsub = tid >> 5;
  const float pmv = pm[g];
  const float pvv = __expf(plv[g]);
  const float wj = w[g * 32 + j];
  const float bj = bias[g * 32 + j];
  const float pterm = PC_ * (pvv + pmv * pmv);
  #pragma unroll
  for (int i = 0; i < 16; ++i) {
    const int l = blockIdx.y * 128 + i * 8 + lsub;
    const size_t idx = ((size_t)(b * L_ + l)) * D_ + g * 32 + j;
    const float v = x[idx];
    const float cnt = PC_ + 32.f * (float)(l + 1);
    const float mean = (PC_ * pmv + s1g[(size_t)bg * L_ + l]) / cnt;
    const float var = (pterm + s2g[(size_t)bg * L_ + l]) / cnt - mean * mean;
    xn[idx] = f2bf((v - mean) * rsqrtf(var + EPS_) * wj + bj);
  }
}

// ---------------- generic 32x32-tiled transpose, batched over z ----------------
template <typename T>
__global__ __launch_bounds__(256) void k_transpose(const T* __restrict__ src,
                                                   T* __restrict__ dst, int R, int C) {
  __shared__ T tile[32][33];
  const size_t batch = (size_t)R * C * blockIdx.z;
  const int c0 = blockIdx.x * 32, r0 = blockIdx.y * 32;
  const int tx = threadIdx.x & 31, ty = threadIdx.x >> 5;
  #pragma unroll
  for (int k = 0; k < 4; ++k) {
    int r = ty + k * 8;
    tile[r][tx] = src[batch + (size_t)(r0 + r) * C + c0 + tx];
  }
  __syncthreads();
  #pragma unroll
  for (int k = 0; k < 4; ++k) {
    int r = ty + k * 8;
    dst[batch + (size_t)(c0 + r) * R + r0 + tx] = tile[tx][r];
  }
}

// ---------------- MultiHeadEMA via chunked linear recurrence ----------------
__global__ __launch_bounds__(64) void k_ema(const uint16_t* __restrict__ xnT,
                                            const float* __restrict__ delta,
                                            const float* __restrict__ alpha,
                                            const float* __restrict__ beta,
                                            const float* __restrict__ gamma,
                                            const float* __restrict__ omega,
                                            float* __restrict__ mxT) {
  __shared__ float hst[64 * NE_];
  const int bd = blockIdx.x;
  const int d = bd & (D_ - 1);
  const int c = threadIdx.x;

  float q[NE_], pb[NE_], gs[NE_];
  #pragma unroll
  for (int n = 0; n < NE_; ++n) {
    float p = sigmoidf_(delta[d * NE_ + n]);
    float a = sigmoidf_(alpha[d * NE_ + n]);
    q[n] = 1.f - p * a;
    pb[n] = p * beta[d * NE_ + n];
    gs[n] = gamma[d * NE_ + n] * 0.25f;
  }

  const uint16_t* xp = xnT + (size_t)bd * L_ + c * 32;
  bf16x8 xin[4];
  #pragma unroll
  for (int s = 0; s < 4; ++s) xin[s] = *(const bf16x8*)(xp + s * 8);

  float h[NE_];
  #pragma unroll
  for (int n = 0; n < NE_; ++n) h[n] = 0.f;

  #pragma unroll
  for (int k = 0; k < 32; ++k) {
    float xv = bf2f((uint16_t)xin[k >> 3][k & 7]);
    #pragma unroll
    for (int n = 0; n < NE_; ++n) h[n] = fmaf(q[n], h[n], pb[n] * xv);
  }
  #pragma unroll
  for (int n = 0; n < NE_; ++n) hst[c * NE_ + n] = h[n];
  __syncthreads();

  if (c < NE_) {
    float qq = q[c];
    float q32 = qq * qq; q32 *= q32; q32 *= q32; q32 *= q32; q32 *= q32;  // q^32
    float hi = 0.f;
    for (int cc = 0; cc < 64; ++cc) {
      float cur = hst[cc * NE_ + c];
      hst[cc * NE_ + c] = hi;
      hi = fmaf(q32, hi, cur);
    }
  }
  __syncthreads();

  #pragma unroll
  for (int n = 0; n < NE_; ++n) h[n] = hst[c * NE_ + n];
  const float om = omega[d];
  float* op = mxT + (size_t)bd * L_ + c * 32;
  f32x4 ov;
  #pragma unroll
  for (int k = 0; k < 32; ++k) {
    float xv = bf2f((uint16_t)xin[k >> 3][k & 7]);
    float accv = 0.f;
    #pragma unroll
    for (int n = 0; n < NE_; ++n) {
      h[n] = fmaf(q[n], h[n], pb[n] * xv);
      accv = fmaf(gs[n], h[n], accv);
    }
    ov[k & 3] = accv + om * xv;
    if ((k & 3) == 3) *(f32x4*)(op + (k & ~3)) = ov;
  }
}

// ---------------- RMS norm over D ----------------
__global__ __launch_bounds__(256) void k_rms(const float* __restrict__ mx,
                                             const float* __restrict__ w,
                                             uint16_t* __restrict__ mxn) {
  __shared__ float red[4];
  const size_t row = blockIdx.x;
  const int tid = threadIdx.x;
  float ss = 0.f;
  #pragma unroll
  for (int i = 0; i < 4; ++i) {
    float v = mx[row * D_ + tid + i * 256];
    ss += v * v;
  }
  ss = waveRedSum(ss);
  if ((tid & 63) == 0) red[tid >> 6] = ss;
  __syncthreads();
  ss = red[0] + red[1] + red[2] + red[3];
  const float scale = rsqrtf(ss * (1.f / D_) + EPS_);
  #pragma unroll
  for (int i = 0; i < 4; ++i) {
    int dcol = tid + i * 256;
    mxn[row * D_ + dcol] = f2bf(mx[row * D_ + dcol] * scale * w[dcol]);
  }
}

// ---------------- q/k prep from z ----------------
__global__ __launch_bounds__(256) void k_qkprep(const float* __restrict__ z,
                                                const float* __restrict__ qg,
                                                const float* __restrict__ qb,
                                                uint16_t* __restrict__ q,
                                                uint16_t* __restrict__ k, int n) {
  for (int i = blockIdx.x * 256 + threadIdx.x; i < n; i += gridDim.x * 256) {
    int zc = i & (Z_ - 1);
    float v = z[i];
    q[i] = f2bf((v * qg[zc] + qb[zc]) * 0.08838834764831845f);
    k[i] = f2bf(v * qg[Z_ + zc] + qb[Z_ + zc]);
  }
}

// ==================================================================
// 256x256-tile, BK=64, 8-wave, 2-phase prefetch GEMM (T3 minimum recipe,
// measured 655-682 TF @ 256^2/K=1024 in m230/m248):
//   per K-tile: STAGE(next tile) -> compute(current) -> __syncthreads()
// Exactly one vmcnt(0)+barrier per K-tile (emitted by __syncthreads);
// the 8 prefetch loads get a full tile of compute (~128 MFMA/wave) of
// issue-to-wait distance.  Linear LDS (bank conflicts are timing-
// irrelevant at 2-phase: m252), no setprio (null at 2ph: m190).
//
// C = A(MxK) @ B(NxK)^T, fused epilogues:
//  MODE 0: V     out = silu(acc + bv[col])               -> bf16 v
//  MODE 1: BASE  acc + bmx[col], split u/z/r/hx (col-guarded at NMX_)
//  MODE 4: WH    g=silu(acc+hx); out = x + u*(g-x)        -> f32 d_out
//
// LDS: buf c at c*32768 (uint16 elems): A[256][64] at +0, B[256][64] at
// +16384.  Staging: thread t covers rows {q*64 + (t>>3)}, 16B granule
// (t&7); LDS dst = base + q*4096 + t*8 (wave-uniform + lane*16B).
// ==================================================================

template <int MODE>
__global__ __launch_bounds__(512, 2) void k_gemm256(
    const uint16_t* __restrict__ A, const uint16_t* __restrict__ Bm,
    int N, int K,
    const float* __restrict__ bias,
    float* __restrict__ outf, uint16_t* __restrict__ outb,
    uint16_t* __restrict__ ubuf, float* __restrict__ zbuf,
    uint16_t* __restrict__ rbuf, float* __restrict__ hxbuf,
    const float* __restrict__ x0) {
  __shared__ uint16_t sm[65536];  // 128 KiB
  const int t = threadIdx.x;
  const int lane = t & 63, wave = t >> 6;
  const int quad = lane >> 4, r16 = lane & 15;
  const int wm = wave >> 2, wn = wave & 3;
  const int bm = blockIdx.x * 256;
  const int bn = blockIdx.y * 256;

  f32x4 acc[8][4];
  const f32x4 zf = {0.f, 0.f, 0.f, 0.f};
  #pragma unroll
  for (int i = 0; i < 8; ++i)
    #pragma unroll
    for (int j = 0; j < 4; ++j) acc[i][j] = zf;

  // staging: thread t -> rows q*64 + (t>>3), granule t&7 (16B), q = 0..3
  const uint16_t* gA = A + (size_t)(bm + (t >> 3)) * K + (t & 7) * 8;
  const uint16_t* gB = Bm + (size_t)(bn + (t >> 3)) * K + (t & 7) * 8;
  const size_t qstep = (size_t)64 * K;
  uint16_t* lA = sm + t * 8;
  uint16_t* lB = sm + 16384 + t * 8;

  // fragment read offsets (linear [256][64] row-major per matrix)
  const int aBase = (wm * 128 + r16) * 64 + quad * 8;
  const int bBase = 16384 + (wn * 64 + r16) * 64 + quad * 8;

#define STAGE(c, kb) do {                                                     \
    _Pragma("unroll")                                                         \
    for (int q = 0; q < 4; ++q) {                                             \
      gl2lds(gA + q * qstep + (kb), lA + (c) * 32768 + q * 4096);             \
      gl2lds(gB + q * qstep + (kb), lB + (c) * 32768 + q * 4096);             \
    }                                                                         \
  } while (0)

  const int NT = K >> 6;

  STAGE(0, 0);
  __syncthreads();  // vmcnt(0) drain + barrier

  bf16x8 af[4], bfr[4];
  for (int tt = 0; tt < NT; ++tt) {
    const int c = tt & 1;
    const int co = c * 32768;
    if (tt + 1 < NT) STAGE(c ^ 1, (tt + 1) * 64);  // prefetch next tile
    #pragma unroll
    for (int kh = 0; kh < 2; ++kh) {
      #pragma unroll
      for (int ih = 0; ih < 2; ++ih) {
        #pragma unroll
        for (int i = 0; i < 4; ++i)
          af[i] = *(const bf16x8*)&sm[co + aBase + (ih * 4 + i) * 1024 + kh * 32];
        #pragma unroll
        for (int j = 0; j < 4; ++j)
          bfr[j] = *(const bf16x8*)&sm[co + bBase + j * 1024 + kh * 32];
        #pragma unroll
        for (int i = 0; i < 4; ++i)
          #pragma unroll
          for (int j = 0; j < 4; ++j)
            acc[ih * 4 + i][j] = __builtin_amdgcn_mfma_f32_16x16x32_bf16(
                af[i], bfr[j], acc[ih * 4 + i][j], 0, 0, 0);
      }
    }
    __syncthreads();  // single vmcnt(0)+barrier per K-tile
  }
#undef STAGE

  // ---- epilogue ----
  #pragma unroll
  for (int gi = 0; gi < 8; ++gi) {
    #pragma unroll
    for (int j = 0; j < 4; ++j) {
      #pragma unroll
      for (int r = 0; r < 4; ++r) {
        const int row = bm + wm * 128 + gi * 16 + quad * 4 + r;
        const int col = bn + wn * 64 + j * 16 + r16;
        float val = acc[gi][j][r];
        if (MODE == 0) {
          outb[(size_t)row * N + col] = f2bf(siluf_(val + bias[col]));
        } else if (MODE == 1) {
          if (col < NMX_) {
            val += bias[col];
            if (col < D_)                 ubuf[(size_t)row * D_ + col] = f2bf(sigmoidf_(val));
            else if (col < D_ + Z_)       zbuf[(size_t)row * Z_ + (col - D_)] = siluf_(val);
            else if (col < D_ + Z_ + H_)  rbuf[(size_t)row * H_ + (col - D_ - Z_)] = f2bf(siluf_(val));
            else                          hxbuf[(size_t)row * D_ + (col - D_ - Z_ - H_)] = val;
          }
        } else {
          const size_t idx = (size_t)row * N + col;
          float g = siluf_(val + hxbuf[idx]);   // read hx (d_out) ...
          float xv = x0[idx];
          outf[idx] = xv + bf2f(ubuf[idx]) * (g - xv);  // ... then write same addr
        }
      }
    }
  }
}

// ---- fused QK^T + rel_bias + causal softmax -> packed-triangular P (bf16) ----
__global__ __launch_bounds__(256) void k_qksm(
    const uint16_t* __restrict__ qg, const uint16_t* __restrict__ kg,
    const float* __restrict__ relb, uint16_t* __restrict__ Pp) {
  __shared__ uint16_t Ks[128 * 128];
  __shared__ float relwin[256];
  const int qt = blockIdx.x;
  const int bl = blockIdx.y;
  const int tid = threadIdx.x;
  const int w = tid >> 6, lane = tid & 63;
  const int quad = lane >> 4, r16 = lane & 15;
  const uint16_t* qb_b = qg + (size_t)bl * L_ * Z_;
  const uint16_t* kb_b = kg + (size_t)bl * L_ * Z_;
  uint16_t* P_b = Pp + (size_t)bl * NPACK_ * TILE_ELEMS_;

  bf16x8 aq[2][4];
  #pragma unroll
  for (int i = 0; i < 2; ++i)
    #pragma unroll
    for (int s = 0; s < 4; ++s)
      aq[i][s] = *(const bf16x8*)&qb_b[(size_t)(qt * 128 + w * 32 + i * 16 + r16) * Z_ +
                                       s * 32 + quad * 8];

  float m8[8], l8[8];
  #pragma unroll
  for (int t = 0; t < 8; ++t) { m8[t] = -3.4e38f; l8[t] = 0.f; }

  const f32x4 zf = {0.f, 0.f, 0.f, 0.f};

  // ---- phase 1: stats ----
  for (int kt = 0; kt <= qt; ++kt) {
    __syncthreads();
    const uint16_t* src = kb_b + (size_t)kt * 128 * Z_;
    #pragma unroll
    for (int s2 = 0; s2 < 8; ++s2)
      gl2lds(src + s2 * 2048 + tid * 8, Ks + s2 * 2048 + tid * 8);
    if (tid < 255) relwin[tid] = relb[2047 + (kt - qt) * 128 - 127 + tid];
    __syncthreads();
    #pragma unroll
    for (int j = 0; j < 8; ++j) {
      f32x4 a0 = zf, a1 = zf;
      #pragma unroll
      for (int s = 0; s < 4; ++s) {
        bf16x8 bk = *(const bf16x8*)&Ks[(j * 16 + r16) * 128 + s * 32 + quad * 8];
        a0 = __builtin_amdgcn_mfma_f32_16x16x32_bf16(aq[0][s], bk, a0, 0, 0, 0);
        a1 = __builtin_amdgcn_mfma_f32_16x16x32_bf16(aq[1][s], bk, a1, 0, 0, 0);
      }
      #pragma unroll
      for (int i = 0; i < 2; ++i) {
        const f32x4 av = i ? a1 : a0;
        #pragma unroll
        for (int r = 0; r < 4; ++r) {
          const int rloc = w * 32 + i * 16 + quad * 4 + r;
          const int cloc = j * 16 + r16;
          if (kt < qt || cloc <= rloc) {
            const float v = av[r] + relwin[cloc - rloc + 127];
            const int t = i * 4 + r;
            const float mn = fmaxf(m8[t], v);
            l8[t] = l8[t] * __expf(m8[t] - mn) + __expf(v - mn);
            m8[t] = mn;
          }
        }
      }
    }
  }

  #pragma unroll
  for (int t = 0; t < 8; ++t) {
    #pragma unroll
    for (int msk = 1; msk <= 8; msk <<= 1) {
      const float mo = __shfl_xor(m8[t], msk, 64);
      const float lo = __shfl_xor(l8[t], msk, 64);
      const float mn = fmaxf(m8[t], mo);
      l8[t] = l8[t] * __expf(m8[t] - mn) + lo * __expf(mo - mn);
      m8[t] = mn;
    }
    l8[t] = 1.f / l8[t];
  }

  // ---- phase 2: recompute, normalize, write packed P ----
  for (int kt = 0; kt <= qt; ++kt) {
    __syncthreads();
    const uint16_t* src = kb_b + (size_t)kt * 128 * Z_;
    #pragma unroll
    for (int s2 = 0; s2 < 8; ++s2)
      gl2lds(src + s2 * 2048 + tid * 8, Ks + s2 * 2048 + tid * 8);
    if (tid < 255) relwin[tid] = relb[2047 + (kt - qt) * 128 - 127 + tid];
    __syncthreads();
    uint16_t* Pt = P_b + (size_t)(qt * (qt + 1) / 2 + kt) * TILE_ELEMS_;
    #pragma unroll
    for (int j = 0; j < 8; ++j) {
      f32x4 a0 = zf, a1 = zf;
      #pragma unroll
      for (int s = 0; s < 4; ++s) {
        bf16x8 bk = *(const bf16x8*)&Ks[(j * 16 + r16) * 128 + s * 32 + quad * 8];
        a0 = __builtin_amdgcn_mfma_f32_16x16x32_bf16(aq[0][s], bk, a0, 0, 0, 0);
        a1 = __builtin_amdgcn_mfma_f32_16x16x32_bf16(aq[1][s], bk, a1, 0, 0, 0);
      }
      #pragma unroll
      for (int i = 0; i < 2; ++i) {
        const f32x4 av = i ? a1 : a0;
        #pragma unroll
        for (int r = 0; r < 4; ++r) {
          const int rloc = w * 32 + i * 16 + quad * 4 + r;
          const int cloc = j * 16 + r16;
          const int t = i * 4 + r;
          float p = 0.f;
          if (kt < qt || cloc <= rloc) {
            const float v = av[r] + relwin[cloc - rloc + 127];
            p = __expf(v - m8[t]) * l8[t];
          }
          Pt[rloc * 128 + cloc] = f2bf(p);
        }
      }
    }
  }
}

// ---- PV GEMM: hr = (P @ V) * r, packed-triangular P, in-place over r ----
__global__ __launch_bounds__(256) void k_pv(
    const uint16_t* __restrict__ Pp, const uint16_t* __restrict__ vT,
    uint16_t* __restrict__ rh) {
  __shared__ uint16_t As[128 * 32];
  __shared__ uint16_t Bs[128 * 32];
  const int qt = blockIdx.x;
  const int bn = blockIdx.y * 128;
  const int bl = blockIdx.z;
  const uint16_t* P_b = Pp + (size_t)bl * NPACK_ * TILE_ELEMS_;
  const uint16_t* v_b = vT + (size_t)bl * H_ * L_;
  uint16_t* rh_b = rh + (size_t)bl * L_ * H_;

  const int tid = threadIdx.x;
  const int wave = tid >> 6, lane = tid & 63;
  const int quad = lane >> 4, r16 = lane & 15;
  const int wm = wave >> 1, wn = wave & 1;
  const int rowW = wm * 64, colW = wn * 64;

  f32x4 acc[4][4];
  const f32x4 zf = {0.f, 0.f, 0.f, 0.f};
  #pragma unroll
  for (int i = 0; i < 4; ++i)
    #pragma unroll
    for (int j = 0; j < 4; ++j) acc[i][j] = zf;

  const int rA = tid >> 2;
  const int sg = (tid & 3) * 8;
  uint16_t* lA0 = As + tid * 8;
  uint16_t* lA1 = As + 2048 + tid * 8;
  uint16_t* lB0 = Bs + tid * 8;
  uint16_t* lB1 = Bs + 2048 + tid * 8;

  for (int kt = 0; kt <= qt; ++kt) {
    const uint16_t* At = P_b + (size_t)(qt * (qt + 1) / 2 + kt) * TILE_ELEMS_;
    #pragma unroll
    for (int ks = 0; ks < 4; ++ks) {
      const int kb = kt * 128 + ks * 32;
      __syncthreads();
      gl2lds(At + rA * 128 + ks * 32 + sg, lA0);
      gl2lds(At + (rA + 64) * 128 + ks * 32 + sg, lA1);
      gl2lds(v_b + (size_t)(bn + rA) * L_ + kb + sg, lB0);
      gl2lds(v_b + (size_t)(bn + 64 + rA) * L_ + kb + sg, lB1);
      __syncthreads();
      bf16x8 af[4], bfr[4];
      #pragma unroll
      for (int i = 0; i < 4; ++i)
        af[i] = *(const bf16x8*)&As[(rowW + i * 16 + r16) * 32 + quad * 8];
      #pragma unroll
      for (int j = 0; j < 4; ++j)
        bfr[j] = *(const bf16x8*)&Bs[(colW + j * 16 + r16) * 32 + quad * 8];
      #pragma unroll
      for (int i = 0; i < 4; ++i)
        #pragma unroll
        for (int j = 0; j < 4; ++j)
          acc[i][j] = __builtin_amdgcn_mfma_f32_16x16x32_bf16(af[i], bfr[j], acc[i][j], 0, 0, 0);
    }
  }

  #pragma unroll
  for (int i = 0; i < 4; ++i) {
    #pragma unroll
    for (int j = 0; j < 4; ++j) {
      #pragma unroll
      for (int r = 0; r < 4; ++r) {
        const int row = qt * 128 + rowW + i * 16 + quad * 4 + r;
        const int col = bn + colW + j * 16 + r16;
        const size_t idx = (size_t)row * H_ + col;
        const float rv = bf2f(rh_b[idx]);
        rh_b[idx] = f2bf(acc[i][j][r] * rv);
      }
    }
  }
}

extern "C" void kernel_launch(void* const* d_in, const int* in_sizes, int n_in,
                              void* d_out, int out_size, void* d_ws, size_t ws_size,
                              hipStream_t stream) {
  (void)in_sizes; (void)n_in;
  const float* x         = (const float*)d_in[0];
  const float* prior_mean= (const float*)d_in[1];
  const float* prior_logv= (const float*)d_in[2];
  const float* tn_w      = (const float*)d_in[3];
  const float* tn_b      = (const float*)d_in[4];
  const float* delta     = (const float*)d_in[5];
  const float* alpha     = (const float*)d_in[6];
  const float* ema_beta  = (const float*)d_in[7];
  const float* ema_gamma = (const float*)d_in[8];
  const float* omega     = (const float*)d_in[9];
  const float* rms_w     = (const float*)d_in[10];
  const float* Wv        = (const float*)d_in[11];
  const float* bv        = (const float*)d_in[12];
  const float* Wmx       = (const float*)d_in[13];
  const float* bmx       = (const float*)d_in[14];
  const float* Wh        = (const float*)d_in[15];
  const float* qk_gamma  = (const float*)d_in[16];
  const float* qk_beta   = (const float*)d_in[17];
  const float* rel_bias  = (const float*)d_in[18];
  float* out = (float*)d_out;

  const int BL = B_ * L_;
  const size_t MB = 1024 * 1024;
  const size_t REQUIRED = 256 * MB;

  if (ws_size < REQUIRED) {
    k_fallback<<<dim3(4096), dim3(256), 0, stream>>>(out, out_size, (float)(ws_size / MB));
    return;
  }

  char* p = (char*)d_ws;
  // A [0,32): xn (bf16) -> ubuf (bf16)
  uint16_t* xn   = (uint16_t*)(p);
  uint16_t* ubuf = (uint16_t*)(p);
  // B [32,64): s1s2 (4MB, tnorm only) -> xnT -> mxn
  float*    s1g  = (float*)   (p + 32 * MB);
  float*    s2g  = (float*)   (p + 34 * MB);
  uint16_t* xnT  = (uint16_t*)(p + 32 * MB);
  uint16_t* mxn  = (uint16_t*)(p + 32 * MB);
  // C [64,128): vbuf -> mx (f32) -> rbuf/hr (in-place PV)
  uint16_t* vbuf = (uint16_t*)(p + 64 * MB);
  float*    mx   = (float*)   (p + 64 * MB);
  uint16_t* rbuf = (uint16_t*)(p + 64 * MB);
  // D [128,192): wv_b -> vT
  uint16_t* wv_b = (uint16_t*)(p + 128 * MB);
  uint16_t* vT   = (uint16_t*)(p + 128 * MB);
  // E [192,256): wmx_b(8.91, padded) | z(8) | qb(4) | kb(4) | Ppack(35.65)
  uint16_t* wmx_b = (uint16_t*)(p + 192 * MB);
  uint16_t* wh_b  = (uint16_t*)(p + 192 * MB);
  float*    zb    = (float*)   (p + 201 * MB);
  uint16_t* qb    = (uint16_t*)(p + 209 * MB);
  uint16_t* kb2   = (uint16_t*)(p + 213 * MB);
  uint16_t* Ppack = (uint16_t*)(p + 217 * MB);
  // d_out doubles as: mxT f32 (EMA out) -> hx f32 (BASE out) -> out
  float* mxT = out;
  float* hx  = out;

  // 1. weights -> bf16 (Wmx padded to NMXP_ rows, zero-filled)
  k_f2bf<<<dim3(1024), dim3(256), 0, stream>>>(Wv, wv_b, H_ * D_);
  k_f2bf_pad<<<dim3(2048), dim3(256), 0, stream>>>(Wmx, wmx_b, NMX_ * D_, NMXP_ * D_);
  // 2. timestep norm (3-phase parallel) -> xn
  k_tnsum<<<dim3(B_ * G_, 16), dim3(256), 0, stream>>>(x, s1g, s2g);
  k_tnscan<<<dim3(B_ * G_), dim3(64), 0, stream>>>(s1g, s2g);
  k_tnnorm<<<dim3(B_ * G_, 16), dim3(256), 0, stream>>>(
      x, s1g, s2g, prior_mean, prior_logv, tn_w, tn_b, xn);
  // 3. xn -> xnT (overwrites dead s1s2)
  k_transpose<uint16_t><<<dim3(D_ / 32, L_ / 32, B_), dim3(256), 0, stream>>>(xn, xnT, L_, D_);
  // 4. v = silu(xn @ Wv^T + bv) -> vbuf
  k_gemm256<0><<<dim3(BL / 256, H_ / 256), dim3(512), 0, stream>>>(
      xn, wv_b, H_, D_, bv, nullptr, vbuf,
      nullptr, nullptr, nullptr, nullptr, nullptr);
  // 5. v -> vT (overwrites dead wv_b)
  k_transpose<uint16_t><<<dim3(H_ / 32, L_ / 32, B_), dim3(256), 0, stream>>>(vbuf, vT, L_, H_);
  // 6. EMA: xnT -> mxT (d_out)
  k_ema<<<dim3(B_ * D_), dim3(64), 0, stream>>>(xnT, delta, alpha, ema_beta, ema_gamma, omega, mxT);
  // 7. mxT -> mx (overwrites dead vbuf)
  k_transpose<float><<<dim3(L_ / 32, D_ / 32, B_), dim3(256), 0, stream>>>(mxT, mx, D_, L_);
  // 8. RMS norm -> mxn (overwrites dead xnT)
  k_rms<<<dim3(BL), dim3(256), 0, stream>>>(mx, rms_w, mxn);
  // 9. BASE GEMM -> u(A), z(E), r(C), hx(d_out)
  k_gemm256<1><<<dim3(BL / 256, NMXP_ / 256), dim3(512), 0, stream>>>(
      mxn, wmx_b, NMXP_, D_, bmx, nullptr, nullptr,
      ubuf, zb, rbuf, hx, nullptr);
  // 10. q,k from z
  k_qkprep<<<dim3(1024), dim3(256), 0, stream>>>(zb, qk_gamma, qk_beta, qb, kb2, BL * Z_);
  // 11. fused QK+softmax -> packed P (all 8 batches, one dispatch)
  k_qksm<<<dim3(NTILE_, B_), dim3(256), 0, stream>>>(qb, kb2, rel_bias, Ppack);
  // 12. PV GEMM, hr = (P@V)*r in-place over rbuf (one dispatch)
  k_pv<<<dim3(NTILE_, H_ / 128, B_), dim3(256), 0, stream>>>(Ppack, vT, rbuf);
  // 13. Wh -> bf16 (over dead wmx_b)
  k_f2bf<<<dim3(1024), dim3(256), 0, stream>>>(Wh, wh_b, D_ * H_);
  // 14. final: g = silu(hx + hr@Wh^T); out = x + u*(g-x)
  k_gemm256<4><<<dim3(BL / 256, D_ / 256), dim3(512), 0, stream>>>(
      rbuf, wh_b, D_, H_, nullptr, out, nullptr,
      ubuf, nullptr, nullptr, hx, x);
}

// Round 3
// 1209.928 us; speedup vs baseline: 1.3261x; 1.0524x over previous
//
#include <hip/hip_runtime.h>
#include <stdint.h>

#define B_ 8
#define L_ 2048
#define D_ 1024
#define Z_ 128
#define H_ 2048
#define NE_ 16
#define G_ 32
#define MAXPOS_ 2048
#define NMX_ 4224   // D + Z + H + D (u | z | r | hx)
#define NMXP_ 4352  // NMX_ padded to multiple of 256 for 256-tile GEMM
#define EPS_ 1e-5f
#define PC_ 2.0f
#define NTILE_ 16            // L/128 q-tiles
#define NPACK_ 136           // 16*17/2 packed causal tiles
#define TILE_ELEMS_ 16384    // 128*128

typedef short bf16x8 __attribute__((ext_vector_type(8)));
typedef float f32x4 __attribute__((ext_vector_type(4)));

__device__ __forceinline__ float bf2f(uint16_t u) {
  union { uint32_t u; float f; } v; v.u = ((uint32_t)u) << 16; return v.f;
}
__device__ __forceinline__ uint16_t f2bf(float f) {
  union { float f; uint32_t u; } v; v.f = f;
  uint32_t r = (v.u + 0x7FFFu + ((v.u >> 16) & 1u)) >> 16;
  return (uint16_t)r;
}
__device__ __forceinline__ float sigmoidf_(float x) { return 1.f / (1.f + __expf(-x)); }
__device__ __forceinline__ float siluf_(float x) { return x / (1.f + __expf(-x)); }

__device__ __forceinline__ float waveRedSum(float v) {
  #pragma unroll
  for (int m = 32; m; m >>= 1) v += __shfl_xor(v, m, 64);
  return v;
}

// async global->LDS, 16 bytes per lane; lds dst must be waveBase + lane*16
__device__ __forceinline__ void gl2lds(const uint16_t* g, uint16_t* l) {
  __builtin_amdgcn_global_load_lds(
      (const __attribute__((address_space(1))) void*)g,
      (__attribute__((address_space(3))) void*)l, 16, 0, 0);
}

// ---------------- fallback when workspace too small ----------------
__global__ __launch_bounds__(256) void k_fallback(float* __restrict__ out, int n, float wsmb) {
  for (int i = blockIdx.x * 256 + threadIdx.x; i < n; i += gridDim.x * 256)
    out[i] = (i == 0) ? wsmb : 0.f;
}

// ---------------- fp32 -> bf16 conversion (weights) ----------------
__global__ __launch_bounds__(256) void k_f2bf(const float* __restrict__ src,
                                              uint16_t* __restrict__ dst, int n) {
  for (int i = blockIdx.x * 256 + threadIdx.x; i < n; i += gridDim.x * 256)
    dst[i] = f2bf(src[i]);
}

// same but zero-fills [n, ntot) (row padding for 256-tile GEMM)
__global__ __launch_bounds__(256) void k_f2bf_pad(const float* __restrict__ src,
                                                  uint16_t* __restrict__ dst, int n, int ntot) {
  for (int i = blockIdx.x * 256 + threadIdx.x; i < ntot; i += gridDim.x * 256)
    dst[i] = (i < n) ? f2bf(src[i]) : (uint16_t)0;
}

// ---------------- TimestepNorm, parallel 3-phase ----------------
__global__ __launch_bounds__(256) void k_tnsum(const float* __restrict__ x,
                                               float* __restrict__ s1g,
                                               float* __restrict__ s2g) {
  const int bg = blockIdx.x;
  const int b = bg / G_, g = bg % G_;
  const int tid = threadIdx.x;
  const int j = tid & 31;
  const int lsub = tid >> 5;
  #pragma unroll
  for (int i = 0; i < 16; ++i) {
    const int l = blockIdx.y * 128 + i * 8 + lsub;
    float v = x[((size_t)(b * L_ + l)) * D_ + g * 32 + j];
    float a = v, sq = v * v;
    #pragma unroll
    for (int m = 1; m <= 16; m <<= 1) { a += __shfl_xor(a, m, 64); sq += __shfl_xor(sq, m, 64); }
    if (j == 0) { s1g[(size_t)bg * L_ + l] = a; s2g[(size_t)bg * L_ + l] = sq; }
  }
}

__global__ __launch_bounds__(64) void k_tnscan(float* __restrict__ s1g,
                                               float* __restrict__ s2g) {
  const int bg = blockIdx.x;
  const int lane = threadIdx.x;
  #pragma unroll
  for (int pass = 0; pass < 2; ++pass) {
    float* gp = (pass ? s2g : s1g) + (size_t)bg * L_;
    float loc[32];
    const int b0 = lane * 32;
    float tot = 0.f;
    #pragma unroll
    for (int t = 0; t < 32; ++t) { loc[t] = gp[b0 + t]; tot += loc[t]; }
    float incl = tot;
    #pragma unroll
    for (int off = 1; off < 64; off <<= 1) {
      float nv = __shfl_up(incl, off, 64);
      if (lane >= off) incl += nv;
    }
    float run = incl - tot;
    #pragma unroll
    for (int t = 0; t < 32; ++t) { run += loc[t]; gp[b0 + t] = run; }
  }
}

__global__ __launch_bounds__(256) void k_tnnorm(const float* __restrict__ x,
                                                const float* __restrict__ s1g,
                                                const float* __restrict__ s2g,
                                                const float* __restrict__ pm,
                                                const float* __restrict__ plv,
                                                const float* __restrict__ w,
                                                const float* __restrict__ bias,
                                                uint16_t* __restrict__ xn) {
  const int bg = blockIdx.x;
  const int b = bg / G_, g = bg % G_;
  const int tid = threadIdx.x;
  const int j = tid & 31;
  const int lsub = tid >> 5;
  const float pmv = pm[g];
  const float pvv = __expf(plv[g]);
  const float wj = w[g * 32 + j];
  const float bj = bias[g * 32 + j];
  const float pterm = PC_ * (pvv + pmv * pmv);
  #pragma unroll
  for (int i = 0; i < 16; ++i) {
    const int l = blockIdx.y * 128 + i * 8 + lsub;
    const size_t idx = ((size_t)(b * L_ + l)) * D_ + g * 32 + j;
    const float v = x[idx];
    const float cnt = PC_ + 32.f * (float)(l + 1);
    const float mean = (PC_ * pmv + s1g[(size_t)bg * L_ + l]) / cnt;
    const float var = (pterm + s2g[(size_t)bg * L_ + l]) / cnt - mean * mean;
    xn[idx] = f2bf((v - mean) * rsqrtf(var + EPS_) * wj + bj);
  }
}

// ---------------- generic 32x32-tiled transpose, batched over z ----------------
template <typename T>
__global__ __launch_bounds__(256) void k_transpose(const T* __restrict__ src,
                                                   T* __restrict__ dst, int R, int C) {
  __shared__ T tile[32][33];
  const size_t batch = (size_t)R * C * blockIdx.z;
  const int c0 = blockIdx.x * 32, r0 = blockIdx.y * 32;
  const int tx = threadIdx.x & 31, ty = threadIdx.x >> 5;
  #pragma unroll
  for (int k = 0; k < 4; ++k) {
    int r = ty + k * 8;
    tile[r][tx] = src[batch + (size_t)(r0 + r) * C + c0 + tx];
  }
  __syncthreads();
  #pragma unroll
  for (int k = 0; k < 4; ++k) {
    int r = ty + k * 8;
    dst[batch + (size_t)(c0 + r) * R + r0 + tx] = tile[tx][r];
  }
}

// ---------------- MultiHeadEMA via chunked linear recurrence ----------------
__global__ __launch_bounds__(64) void k_ema(const uint16_t* __restrict__ xnT,
                                            const float* __restrict__ delta,
                                            const float* __restrict__ alpha,
                                            const float* __restrict__ beta,
                                            const float* __restrict__ gamma,
                                            const float* __restrict__ omega,
                                            float* __restrict__ mxT) {
  __shared__ float hst[64 * NE_];
  const int bd = blockIdx.x;
  const int d = bd & (D_ - 1);
  const int c = threadIdx.x;

  float q[NE_], pb[NE_], gs[NE_];
  #pragma unroll
  for (int n = 0; n < NE_; ++n) {
    float p = sigmoidf_(delta[d * NE_ + n]);
    float a = sigmoidf_(alpha[d * NE_ + n]);
    q[n] = 1.f - p * a;
    pb[n] = p * beta[d * NE_ + n];
    gs[n] = gamma[d * NE_ + n] * 0.25f;
  }

  const uint16_t* xp = xnT + (size_t)bd * L_ + c * 32;
  bf16x8 xin[4];
  #pragma unroll
  for (int s = 0; s < 4; ++s) xin[s] = *(const bf16x8*)(xp + s * 8);

  float h[NE_];
  #pragma unroll
  for (int n = 0; n < NE_; ++n) h[n] = 0.f;

  #pragma unroll
  for (int k = 0; k < 32; ++k) {
    float xv = bf2f((uint16_t)xin[k >> 3][k & 7]);
    #pragma unroll
    for (int n = 0; n < NE_; ++n) h[n] = fmaf(q[n], h[n], pb[n] * xv);
  }
  #pragma unroll
  for (int n = 0; n < NE_; ++n) hst[c * NE_ + n] = h[n];
  __syncthreads();

  if (c < NE_) {
    float qq = q[c];
    float q32 = qq * qq; q32 *= q32; q32 *= q32; q32 *= q32; q32 *= q32;  // q^32
    float hi = 0.f;
    for (int cc = 0; cc < 64; ++cc) {
      float cur = hst[cc * NE_ + c];
      hst[cc * NE_ + c] = hi;
      hi = fmaf(q32, hi, cur);
    }
  }
  __syncthreads();

  #pragma unroll
  for (int n = 0; n < NE_; ++n) h[n] = hst[c * NE_ + n];
  const float om = omega[d];
  float* op = mxT + (size_t)bd * L_ + c * 32;
  f32x4 ov;
  #pragma unroll
  for (int k = 0; k < 32; ++k) {
    float xv = bf2f((uint16_t)xin[k >> 3][k & 7]);
    float accv = 0.f;
    #pragma unroll
    for (int n = 0; n < NE_; ++n) {
      h[n] = fmaf(q[n], h[n], pb[n] * xv);
      accv = fmaf(gs[n], h[n], accv);
    }
    ov[k & 3] = accv + om * xv;
    if ((k & 3) == 3) *(f32x4*)(op + (k & ~3)) = ov;
  }
}

// ---------------- RMS norm over D ----------------
__global__ __launch_bounds__(256) void k_rms(const float* __restrict__ mx,
                                             const float* __restrict__ w,
                                             uint16_t* __restrict__ mxn) {
  __shared__ float red[4];
  const size_t row = blockIdx.x;
  const int tid = threadIdx.x;
  float ss = 0.f;
  #pragma unroll
  for (int i = 0; i < 4; ++i) {
    float v = mx[row * D_ + tid + i * 256];
    ss += v * v;
  }
  ss = waveRedSum(ss);
  if ((tid & 63) == 0) red[tid >> 6] = ss;
  __syncthreads();
  ss = red[0] + red[1] + red[2] + red[3];
  const float scale = rsqrtf(ss * (1.f / D_) + EPS_);
  #pragma unroll
  for (int i = 0; i < 4; ++i) {
    int dcol = tid + i * 256;
    mxn[row * D_ + dcol] = f2bf(mx[row * D_ + dcol] * scale * w[dcol]);
  }
}

// ---------------- q/k prep from z ----------------
__global__ __launch_bounds__(256) void k_qkprep(const float* __restrict__ z,
                                                const float* __restrict__ qg,
                                                const float* __restrict__ qb,
                                                uint16_t* __restrict__ q,
                                                uint16_t* __restrict__ k, int n) {
  for (int i = blockIdx.x * 256 + threadIdx.x; i < n; i += gridDim.x * 256) {
    int zc = i & (Z_ - 1);
    float v = z[i];
    q[i] = f2bf((v * qg[zc] + qb[zc]) * 0.08838834764831845f);
    k[i] = f2bf(v * qg[Z_ + zc] + qb[Z_ + zc]);
  }
}

// ==================================================================
// 256x256-tile, BK=64, 8-wave, 2-phase prefetch GEMM.
//   per K-tile: STAGE(next tile) -> compute(current) -> __syncthreads()
//
// Round-3 changes (LDS-read was the measured critical path, 22% of
// cycles in 16-way bank conflicts):
//  * granule XOR-swizzle (T2, both-sides): LDS row r keeps its 8
//    16B-granules permuted as phys = logical ^ (r&7).  Staging keeps the
//    LDS dest linear (gl2lds requirement) and pre-swizzles the GLOBAL
//    source column; reads apply the same XOR.  16-way -> 2-way (free).
//  * B fragments hoisted out of the row-half loop: 24 instead of 32
//    ds_read_b128 per wave per K-tile.
//
// C = A(MxK) @ B(NxK)^T, fused epilogues:
//  MODE 0: V     out = silu(acc + bv[col])               -> bf16 v
//  MODE 1: BASE  acc + bmx[col], split u/z/r/hx (col-guarded at NMX_)
//  MODE 4: WH    g=silu(acc+hx); out = x + u*(g-x)        -> f32 d_out
//
// LDS: buf c at c*32768 (uint16 elems): A[256][64] at +0, B[256][64] at
// +16384.  Staging thread t covers rows {q*64 + (t>>3)}, phys granule
// (t&7) -> logical granule (t&7)^((t>>3)&7) of that row.
// ==================================================================

template <int MODE>
__global__ __launch_bounds__(512, 2) void k_gemm256(
    const uint16_t* __restrict__ A, const uint16_t* __restrict__ Bm,
    int N, int K,
    const float* __restrict__ bias,
    float* __restrict__ outf, uint16_t* __restrict__ outb,
    uint16_t* __restrict__ ubuf, float* __restrict__ zbuf,
    uint16_t* __restrict__ rbuf, float* __restrict__ hxbuf,
    const float* __restrict__ x0) {
  __shared__ uint16_t sm[65536];  // 128 KiB
  const int t = threadIdx.x;
  const int lane = t & 63, wave = t >> 6;
  const int quad = lane >> 4, r16 = lane & 15;
  const int wm = wave >> 2, wn = wave & 3;
  const int bm = blockIdx.x * 256;
  const int bn = blockIdx.y * 256;

  f32x4 acc[8][4];
  const f32x4 zf = {0.f, 0.f, 0.f, 0.f};
  #pragma unroll
  for (int i = 0; i < 8; ++i)
    #pragma unroll
    for (int j = 0; j < 4; ++j) acc[i][j] = zf;

  // staging: thread t -> rows q*64 + (t>>3); LDS dest linear (granule t&7);
  // global source column pre-swizzled to logical granule (t&7)^((t>>3)&7).
  const int sgz = (((t & 7) ^ ((t >> 3) & 7)) << 3);
  const uint16_t* gA = A + (size_t)(bm + (t >> 3)) * K + sgz;
  const uint16_t* gB = Bm + (size_t)(bn + (t >> 3)) * K + sgz;
  const size_t qstep = (size_t)64 * K;
  uint16_t* lA = sm + t * 8;
  uint16_t* lB = sm + 16384 + t * 8;

  // fragment read offsets: row*64 + (logical_granule ^ (row&7))*8
  // logical granule = kh*4 + quad; row&7 = r16&7 (other row terms are %16==0)
  const int g0 = quad ^ (r16 & 7);                 // phys granule, kh=0
  const int aRowOff = (wm * 128 + r16) * 64;
  const int bRowOff = 16384 + (wn * 64 + r16) * 64;

#define STAGE(c, kb) do {                                                     \
    _Pragma("unroll")                                                         \
    for (int q = 0; q < 4; ++q) {                                             \
      gl2lds(gA + q * qstep + (kb), lA + (c) * 32768 + q * 4096);             \
      gl2lds(gB + q * qstep + (kb), lB + (c) * 32768 + q * 4096);             \
    }                                                                         \
  } while (0)

  const int NT = K >> 6;

  STAGE(0, 0);
  __syncthreads();  // vmcnt(0) drain + barrier

  bf16x8 af[4], bfr[4];
  for (int tt = 0; tt < NT; ++tt) {
    const int c = tt & 1;
    const int co = c * 32768;
    if (tt + 1 < NT) STAGE(c ^ 1, (tt + 1) * 64);  // prefetch next tile
    #pragma unroll
    for (int kh = 0; kh < 2; ++kh) {
      const int ga = (g0 ^ (kh << 2)) * 8;         // phys granule offset
      #pragma unroll
      for (int j = 0; j < 4; ++j)                  // B frags held across ih
        bfr[j] = *(const bf16x8*)&sm[co + bRowOff + j * 1024 + ga];
      #pragma unroll
      for (int ih = 0; ih < 2; ++ih) {
        #pragma unroll
        for (int i = 0; i < 4; ++i)
          af[i] = *(const bf16x8*)&sm[co + aRowOff + (ih * 4 + i) * 1024 + ga];
        #pragma unroll
        for (int i = 0; i < 4; ++i)
          #pragma unroll
          for (int j = 0; j < 4; ++j)
            acc[ih * 4 + i][j] = __builtin_amdgcn_mfma_f32_16x16x32_bf16(
                af[i], bfr[j], acc[ih * 4 + i][j], 0, 0, 0);
      }
    }
    __syncthreads();  // single vmcnt(0)+barrier per K-tile
  }
#undef STAGE

  // ---- epilogue ----
  #pragma unroll
  for (int gi = 0; gi < 8; ++gi) {
    #pragma unroll
    for (int j = 0; j < 4; ++j) {
      #pragma unroll
      for (int r = 0; r < 4; ++r) {
        const int row = bm + wm * 128 + gi * 16 + quad * 4 + r;
        const int col = bn + wn * 64 + j * 16 + r16;
        float val = acc[gi][j][r];
        if (MODE == 0) {
          outb[(size_t)row * N + col] = f2bf(siluf_(val + bias[col]));
        } else if (MODE == 1) {
          if (col < NMX_) {
            val += bias[col];
            if (col < D_)                 ubuf[(size_t)row * D_ + col] = f2bf(sigmoidf_(val));
            else if (col < D_ + Z_)       zbuf[(size_t)row * Z_ + (col - D_)] = siluf_(val);
            else if (col < D_ + Z_ + H_)  rbuf[(size_t)row * H_ + (col - D_ - Z_)] = f2bf(siluf_(val));
            else                          hxbuf[(size_t)row * D_ + (col - D_ - Z_ - H_)] = val;
          }
        } else {
          const size_t idx = (size_t)row * N + col;
          float g = siluf_(val + hxbuf[idx]);   // read hx (d_out) ...
          float xv = x0[idx];
          outf[idx] = xv + bf2f(ubuf[idx]) * (g - xv);  // ... then write same addr
        }
      }
    }
  }
}

// ---- fused QK^T + rel_bias + causal softmax -> packed-triangular P (bf16) ----
// Ks rows are 128 elems (256 B): unswizzled reads are 16-way conflicted.
// Same granule XOR-swizzle: phys granule = logical ^ (row&7); staging
// pre-swizzles the global source column, LDS dest stays linear.
__global__ __launch_bounds__(256) void k_qksm(
    const uint16_t* __restrict__ qg, const uint16_t* __restrict__ kg,
    const float* __restrict__ relb, uint16_t* __restrict__ Pp) {
  __shared__ uint16_t Ks[128 * 128];
  __shared__ float relwin[256];
  const int qt = blockIdx.x;
  const int bl = blockIdx.y;
  const int tid = threadIdx.x;
  const int w = tid >> 6, lane = tid & 63;
  const int quad = lane >> 4, r16 = lane & 15;
  const uint16_t* qb_b = qg + (size_t)bl * L_ * Z_;
  const uint16_t* kb_b = kg + (size_t)bl * L_ * Z_;
  uint16_t* P_b = Pp + (size_t)bl * NPACK_ * TILE_ELEMS_;

  // staging swizzle: row = s2*16 + (tid>>4); phys granule tid&15;
  // logical granule = (tid&15) ^ ((tid>>4)&7)
  const int ksg = (tid >> 4) * 128 + (((tid & 15) ^ ((tid >> 4) & 7)) << 3);
  // read swizzle: row&7 = r16&7 (j*16 term %16==0)
  const int kg7 = r16 & 7;

  bf16x8 aq[2][4];
  #pragma unroll
  for (int i = 0; i < 2; ++i)
    #pragma unroll
    for (int s = 0; s < 4; ++s)
      aq[i][s] = *(const bf16x8*)&qb_b[(size_t)(qt * 128 + w * 32 + i * 16 + r16) * Z_ +
                                       s * 32 + quad * 8];

  float m8[8], l8[8];
  #pragma unroll
  for (int t = 0; t < 8; ++t) { m8[t] = -3.4e38f; l8[t] = 0.f; }

  const f32x4 zf = {0.f, 0.f, 0.f, 0.f};

  // ---- phase 1: stats ----
  for (int kt = 0; kt <= qt; ++kt) {
    __syncthreads();
    const uint16_t* src = kb_b + (size_t)kt * 128 * Z_;
    #pragma unroll
    for (int s2 = 0; s2 < 8; ++s2)
      gl2lds(src + s2 * 2048 + ksg, Ks + s2 * 2048 + tid * 8);
    if (tid < 255) relwin[tid] = relb[2047 + (kt - qt) * 128 - 127 + tid];
    __syncthreads();
    #pragma unroll
    for (int j = 0; j < 8; ++j) {
      f32x4 a0 = zf, a1 = zf;
      #pragma unroll
      for (int s = 0; s < 4; ++s) {
        bf16x8 bk = *(const bf16x8*)&Ks[(j * 16 + r16) * 128 +
                                        (((s * 4 + quad) ^ kg7) << 3)];
        a0 = __builtin_amdgcn_mfma_f32_16x16x32_bf16(aq[0][s], bk, a0, 0, 0, 0);
        a1 = __builtin_amdgcn_mfma_f32_16x16x32_bf16(aq[1][s], bk, a1, 0, 0, 0);
      }
      #pragma unroll
      for (int i = 0; i < 2; ++i) {
        const f32x4 av = i ? a1 : a0;
        #pragma unroll
        for (int r = 0; r < 4; ++r) {
          const int rloc = w * 32 + i * 16 + quad * 4 + r;
          const int cloc = j * 16 + r16;
          if (kt < qt || cloc <= rloc) {
            const float v = av[r] + relwin[cloc - rloc + 127];
            const int t = i * 4 + r;
            const float mn = fmaxf(m8[t], v);
            l8[t] = l8[t] * __expf(m8[t] - mn) + __expf(v - mn);
            m8[t] = mn;
          }
        }
      }
    }
  }

  #pragma unroll
  for (int t = 0; t < 8; ++t) {
    #pragma unroll
    for (int msk = 1; msk <= 8; msk <<= 1) {
      const float mo = __shfl_xor(m8[t], msk, 64);
      const float lo = __shfl_xor(l8[t], msk, 64);
      const float mn = fmaxf(m8[t], mo);
      l8[t] = l8[t] * __expf(m8[t] - mn) + lo * __expf(mo - mn);
      m8[t] = mn;
    }
    l8[t] = 1.f / l8[t];
  }

  // ---- phase 2: recompute, normalize, write packed P ----
  for (int kt = 0; kt <= qt; ++kt) {
    __syncthreads();
    const uint16_t* src = kb_b + (size_t)kt * 128 * Z_;
    #pragma unroll
    for (int s2 = 0; s2 < 8; ++s2)
      gl2lds(src + s2 * 2048 + ksg, Ks + s2 * 2048 + tid * 8);
    if (tid < 255) relwin[tid] = relb[2047 + (kt - qt) * 128 - 127 + tid];
    __syncthreads();
    uint16_t* Pt = P_b + (size_t)(qt * (qt + 1) / 2 + kt) * TILE_ELEMS_;
    #pragma unroll
    for (int j = 0; j < 8; ++j) {
      f32x4 a0 = zf, a1 = zf;
      #pragma unroll
      for (int s = 0; s < 4; ++s) {
        bf16x8 bk = *(const bf16x8*)&Ks[(j * 16 + r16) * 128 +
                                        (((s * 4 + quad) ^ kg7) << 3)];
        a0 = __builtin_amdgcn_mfma_f32_16x16x32_bf16(aq[0][s], bk, a0, 0, 0, 0);
        a1 = __builtin_amdgcn_mfma_f32_16x16x32_bf16(aq[1][s], bk, a1, 0, 0, 0);
      }
      #pragma unroll
      for (int i = 0; i < 2; ++i) {
        const f32x4 av = i ? a1 : a0;
        #pragma unroll
        for (int r = 0; r < 4; ++r) {
          const int rloc = w * 32 + i * 16 + quad * 4 + r;
          const int cloc = j * 16 + r16;
          const int t = i * 4 + r;
          float p = 0.f;
          if (kt < qt || cloc <= rloc) {
            const float v = av[r] + relwin[cloc - rloc + 127];
            p = __expf(v - m8[t]) * l8[t];
          }
          Pt[rloc * 128 + cloc] = f2bf(p);
        }
      }
    }
  }
}

// ---- PV GEMM: hr = (P @ V) * r, packed-triangular P, in-place over r ----
// [128][32] tiles: 4 granules/row, 8-way conflicted unswizzled.
// Granule XOR-swizzle with (row&3): phys = logical ^ (row&3).
__global__ __launch_bounds__(256) void k_pv(
    const uint16_t* __restrict__ Pp, const uint16_t* __restrict__ vT,
    uint16_t* __restrict__ rh) {
  __shared__ uint16_t As[128 * 32];
  __shared__ uint16_t Bs[128 * 32];
  const int qt = blockIdx.x;
  const int bn = blockIdx.y * 128;
  const int bl = blockIdx.z;
  const uint16_t* P_b = Pp + (size_t)bl * NPACK_ * TILE_ELEMS_;
  const uint16_t* v_b = vT + (size_t)bl * H_ * L_;
  uint16_t* rh_b = rh + (size_t)bl * L_ * H_;

  const int tid = threadIdx.x;
  const int wave = tid >> 6, lane = tid & 63;
  const int quad = lane >> 4, r16 = lane & 15;
  const int wm = wave >> 1, wn = wave & 1;
  const int rowW = wm * 64, colW = wn * 64;

  f32x4 acc[4][4];
  const f32x4 zf = {0.f, 0.f, 0.f, 0.f};
  #pragma unroll
  for (int i = 0; i < 4; ++i)
    #pragma unroll
    for (int j = 0; j < 4; ++j) acc[i][j] = zf;

  const int rA = tid >> 2;
  // staging: phys granule tid&3 -> logical (tid&3)^(rA&3); src col pre-swizzled
  const int sg = (((tid & 3) ^ (rA & 3)) << 3);
  // read: phys granule = quad ^ (row&3), row&3 = r16&3
  const int gpv = ((quad ^ (r16 & 3)) << 3);
  uint16_t* lA0 = As + tid * 8;
  uint16_t* lA1 = As + 2048 + tid * 8;
  uint16_t* lB0 = Bs + tid * 8;
  uint16_t* lB1 = Bs + 2048 + tid * 8;

  for (int kt = 0; kt <= qt; ++kt) {
    const uint16_t* At = P_b + (size_t)(qt * (qt + 1) / 2 + kt) * TILE_ELEMS_;
    #pragma unroll
    for (int ks = 0; ks < 4; ++ks) {
      const int kb = kt * 128 + ks * 32;
      __syncthreads();
      gl2lds(At + rA * 128 + ks * 32 + sg, lA0);
      gl2lds(At + (rA + 64) * 128 + ks * 32 + sg, lA1);
      gl2lds(v_b + (size_t)(bn + rA) * L_ + kb + sg, lB0);
      gl2lds(v_b + (size_t)(bn + 64 + rA) * L_ + kb + sg, lB1);
      __syncthreads();
      bf16x8 af[4], bfr[4];
      #pragma unroll
      for (int i = 0; i < 4; ++i)
        af[i] = *(const bf16x8*)&As[(rowW + i * 16 + r16) * 32 + gpv];
      #pragma unroll
      for (int j = 0; j < 4; ++j)
        bfr[j] = *(const bf16x8*)&Bs[(colW + j * 16 + r16) * 32 + gpv];
      #pragma unroll
      for (int i = 0; i < 4; ++i)
        #pragma unroll
        for (int j = 0; j < 4; ++j)
          acc[i][j] = __builtin_amdgcn_mfma_f32_16x16x32_bf16(af[i], bfr[j], acc[i][j], 0, 0, 0);
    }
  }

  #pragma unroll
  for (int i = 0; i < 4; ++i) {
    #pragma unroll
    for (int j = 0; j < 4; ++j) {
      #pragma unroll
      for (int r = 0; r < 4; ++r) {
        const int row = qt * 128 + rowW + i * 16 + quad * 4 + r;
        const int col = bn + colW + j * 16 + r16;
        const size_t idx = (size_t)row * H_ + col;
        const float rv = bf2f(rh_b[idx]);
        rh_b[idx] = f2bf(acc[i][j][r] * rv);
      }
    }
  }
}

extern "C" void kernel_launch(void* const* d_in, const int* in_sizes, int n_in,
                              void* d_out, int out_size, void* d_ws, size_t ws_size,
                              hipStream_t stream) {
  (void)in_sizes; (void)n_in;
  const float* x         = (const float*)d_in[0];
  const float* prior_mean= (const float*)d_in[1];
  const float* prior_logv= (const float*)d_in[2];
  const float* tn_w      = (const float*)d_in[3];
  const float* tn_b      = (const float*)d_in[4];
  const float* delta     = (const float*)d_in[5];
  const float* alpha     = (const float*)d_in[6];
  const float* ema_beta  = (const float*)d_in[7];
  const float* ema_gamma = (const float*)d_in[8];
  const float* omega     = (const float*)d_in[9];
  const float* rms_w     = (const float*)d_in[10];
  const float* Wv        = (const float*)d_in[11];
  const float* bv        = (const float*)d_in[12];
  const float* Wmx       = (const float*)d_in[13];
  const float* bmx       = (const float*)d_in[14];
  const float* Wh        = (const float*)d_in[15];
  const float* qk_gamma  = (const float*)d_in[16];
  const float* qk_beta   = (const float*)d_in[17];
  const float* rel_bias  = (const float*)d_in[18];
  float* out = (float*)d_out;

  const int BL = B_ * L_;
  const size_t MB = 1024 * 1024;
  const size_t REQUIRED = 256 * MB;

  if (ws_size < REQUIRED) {
    k_fallback<<<dim3(4096), dim3(256), 0, stream>>>(out, out_size, (float)(ws_size / MB));
    return;
  }

  char* p = (char*)d_ws;
  // A [0,32): xn (bf16) -> ubuf (bf16)
  uint16_t* xn   = (uint16_t*)(p);
  uint16_t* ubuf = (uint16_t*)(p);
  // B [32,64): s1s2 (4MB, tnorm only) -> xnT -> mxn
  float*    s1g  = (float*)   (p + 32 * MB);
  float*    s2g  = (float*)   (p + 34 * MB);
  uint16_t* xnT  = (uint16_t*)(p + 32 * MB);
  uint16_t* mxn  = (uint16_t*)(p + 32 * MB);
  // C [64,128): vbuf -> mx (f32) -> rbuf/hr (in-place PV)
  uint16_t* vbuf = (uint16_t*)(p + 64 * MB);
  float*    mx   = (float*)   (p + 64 * MB);
  uint16_t* rbuf = (uint16_t*)(p + 64 * MB);
  // D [128,192): wv_b -> vT
  uint16_t* wv_b = (uint16_t*)(p + 128 * MB);
  uint16_t* vT   = (uint16_t*)(p + 128 * MB);
  // E [192,256): wmx_b(8.91, padded) | z(8) | qb(4) | kb(4) | Ppack(35.65)
  uint16_t* wmx_b = (uint16_t*)(p + 192 * MB);
  uint16_t* wh_b  = (uint16_t*)(p + 192 * MB);
  float*    zb    = (float*)   (p + 201 * MB);
  uint16_t* qb    = (uint16_t*)(p + 209 * MB);
  uint16_t* kb2   = (uint16_t*)(p + 213 * MB);
  uint16_t* Ppack = (uint16_t*)(p + 217 * MB);
  // d_out doubles as: mxT f32 (EMA out) -> hx f32 (BASE out) -> out
  float* mxT = out;
  float* hx  = out;

  // 1. weights -> bf16 (Wmx padded to NMXP_ rows, zero-filled)
  k_f2bf<<<dim3(1024), dim3(256), 0, stream>>>(Wv, wv_b, H_ * D_);
  k_f2bf_pad<<<dim3(2048), dim3(256), 0, stream>>>(Wmx, wmx_b, NMX_ * D_, NMXP_ * D_);
  // 2. timestep norm (3-phase parallel) -> xn
  k_tnsum<<<dim3(B_ * G_, 16), dim3(256), 0, stream>>>(x, s1g, s2g);
  k_tnscan<<<dim3(B_ * G_), dim3(64), 0, stream>>>(s1g, s2g);
  k_tnnorm<<<dim3(B_ * G_, 16), dim3(256), 0, stream>>>(
      x, s1g, s2g, prior_mean, prior_logv, tn_w, tn_b, xn);
  // 3. xn -> xnT (overwrites dead s1s2)
  k_transpose<uint16_t><<<dim3(D_ / 32, L_ / 32, B_), dim3(256), 0, stream>>>(xn, xnT, L_, D_);
  // 4. v = silu(xn @ Wv^T + bv) -> vbuf
  k_gemm256<0><<<dim3(BL / 256, H_ / 256), dim3(512), 0, stream>>>(
      xn, wv_b, H_, D_, bv, nullptr, vbuf,
      nullptr, nullptr, nullptr, nullptr, nullptr);
  // 5. v -> vT (overwrites dead wv_b)
  k_transpose<uint16_t><<<dim3(H_ / 32, L_ / 32, B_), dim3(256), 0, stream>>>(vbuf, vT, L_, H_);
  // 6. EMA: xnT -> mxT (d_out)
  k_ema<<<dim3(B_ * D_), dim3(64), 0, stream>>>(xnT, delta, alpha, ema_beta, ema_gamma, omega, mxT);
  // 7. mxT -> mx (overwrites dead vbuf)
  k_transpose<float><<<dim3(L_ / 32, D_ / 32, B_), dim3(256), 0, stream>>>(mxT, mx, D_, L_);
  // 8. RMS norm -> mxn (overwrites dead xnT)
  k_rms<<<dim3(BL), dim3(256), 0, stream>>>(mx, rms_w, mxn);
  // 9. BASE GEMM -> u(A), z(E), r(C), hx(d_out)
  k_gemm256<1><<<dim3(BL / 256, NMXP_ / 256), dim3(512), 0, stream>>>(
      mxn, wmx_b, NMXP_, D_, bmx, nullptr, nullptr,
      ubuf, zb, rbuf, hx, nullptr);
  // 10. q,k from z
  k_qkprep<<<dim3(1024), dim3(256), 0, stream>>>(zb, qk_gamma, qk_beta, qb, kb2, BL * Z_);
  // 11. fused QK+softmax -> packed P (all 8 batches, one dispatch)
  k_qksm<<<dim3(NTILE_, B_), dim3(256), 0, stream>>>(qb, kb2, rel_bias, Ppack);
  // 12. PV GEMM, hr = (P@V)*r in-place over rbuf (one dispatch)
  k_pv<<<dim3(NTILE_, H_ / 128, B_), dim3(256), 0, stream>>>(Ppack, vT, rbuf);
  // 13. Wh -> bf16 (over dead wmx_b)
  k_f2bf<<<dim3(1024), dim3(256), 0, stream>>>(Wh, wh_b, D_ * H_);
  // 14. final: g = silu(hx + hr@Wh^T); out = x + u*(g-x)
  k_gemm256<4><<<dim3(BL / 256, D_ / 256), dim3(512), 0, stream>>>(
      rbuf, wh_b, D_, H_, nullptr, out, nullptr,
      ubuf, nullptr, nullptr, hx, x);
}